// Round 1
// baseline (327.441 us; speedup 1.0000x reference)
//
#include <hip/hip_runtime.h>
#include <hip/hip_bf16.h>
#include <math.h>

// ConvNeXt MLP + parallel MoE-LoRA, fp32 in/out, bf16-tolerance harness.
// B,H,W,C = 64,14,14,768 ; N_tok = 12544 = 98*128 ; HID = 3072 ; E=8,K=2,R=16.
//
//   h  = gelu(x @ w1 + b1)                GEMM1  [12544,768]x[768,3072]
//   sd = wt * gelu(x @ wdown)             GEMMd  [12544,768]x[768,128]
//   out = [h | sd] @ [w2 ; wup] + b2      GEMM2  [12544,3200]x[3200,768]
//
// R13 = R12 + two occupancy fixes (GEMM2 was 636 TF, MfmaUtil 26%,
// Occupancy 21% with only 588 blocks = 2.3/CU -> latency/imbalance bound):
//   1. GEMM2 TM=64: 64x128 tiles, 128 thr, 2 waves (wave tile still 64x64 so
//      per-wave MFMA:ds_read ratio unchanged). 1176 useful blocks = 4.6/CU,
//      24 KB LDS -> 6 resident blocks = 12 waves/CU. XCD swizzle re-derived
//      for 1200-block launch (same-by -> same XCD, consecutive).
//   2. GEMMd merged into GEMM1 as bx==24 column (identical A/lda/ldb/kIters;
//      only B pointer + epilogue differ). Kills the 98-block launch.

#define NTOK   12544
#define CDIM   768
#define HIDDIM 3072
#define KBIG   3200

typedef __attribute__((ext_vector_type(8))) short bf16x8;
typedef __attribute__((ext_vector_type(4))) float f32x4;

#define GLOBAL_AS(p) ((const __attribute__((address_space(1))) void*)(p))
#define LDS_AS(p)    ((__attribute__((address_space(3))) void*)(p))

__device__ inline unsigned short f2bf(float f) {
    unsigned int x = __float_as_uint(f);
    x += 0x7fffu + ((x >> 16) & 1u);   // RNE
    return (unsigned short)(x >> 16);
}

// tanh-form GELU, branch-free; max |err| ~4.3e-4 vs exact erf form.
__device__ inline float gelu_fast(float x) {
    float x3 = x * x * x;
    float u2 = 1.5957691216057308f * x + 0.07135481627260025f * x3;
    float e = __expf(-u2);
    return x * __builtin_amdgcn_rcpf(1.0f + e);
}

// ---------------- fused prep: cast_x + 3 transposes (64x64) + pack_wdown -------
__global__ void __launch_bounds__(256) prep_kernel(
        const float* __restrict__ x, const float* __restrict__ w1,
        const float* __restrict__ w2, const float* __restrict__ wup,
        const float* __restrict__ wdn,
        unsigned short* __restrict__ xb, unsigned short* __restrict__ w1t,
        unsigned short* __restrict__ B2t, unsigned short* __restrict__ wdt) {
    __shared__ float tile[64][65];
    const int b = blockIdx.x, tid = threadIdx.x;
    if (b < 9408) {                      // cast x -> bf16, float4->ushort4
        int i = b * 256 + tid;
        float4 v = ((const float4*)x)[i];
        ushort4 o;
        o.x = f2bf(v.x); o.y = f2bf(v.y); o.z = f2bf(v.z); o.w = f2bf(v.w);
        ((ushort4*)xb)[i] = o;
        return;
    }
    if (b < 10584) {                     // 64x64 transpose tiles
        const float* in; unsigned short* outp; int Ccols, out_ld, out_off, bx, by;
        if (b < 9984)       { int t = b - 9408;  in = w1;  outp = w1t; Ccols = 3072; out_ld = 768;  out_off = 0;    bx = t % 48; by = t / 48; }
        else if (b < 10560) { int t = b - 9984;  in = w2;  outp = B2t; Ccols = 768;  out_ld = 3200; out_off = 0;    bx = t % 12; by = t / 12; }
        else                { int t = b - 10560; in = wup; outp = B2t; Ccols = 768;  out_ld = 3200; out_off = 3072; bx = t % 12; by = t / 12; }
        const int c0 = bx * 64, r0 = by * 64;
        #pragma unroll
        for (int p = 0; p < 4; ++p) {
            int idx = p * 256 + tid;
            int r = idx >> 4, c4 = (idx & 15) * 4;
            float4 v = *(const float4*)&in[(size_t)(r0 + r) * Ccols + c0 + c4];
            tile[r][c4 + 0] = v.x; tile[r][c4 + 1] = v.y;
            tile[r][c4 + 2] = v.z; tile[r][c4 + 3] = v.w;
        }
        __syncthreads();
        #pragma unroll
        for (int p = 0; p < 2; ++p) {
            int u = p * 256 + tid;
            int cc = u >> 3, r8 = (u & 7) * 8;
            uint4 pk;
            pk.x = (unsigned)f2bf(tile[r8 + 0][cc]) | ((unsigned)f2bf(tile[r8 + 1][cc]) << 16);
            pk.y = (unsigned)f2bf(tile[r8 + 2][cc]) | ((unsigned)f2bf(tile[r8 + 3][cc]) << 16);
            pk.z = (unsigned)f2bf(tile[r8 + 4][cc]) | ((unsigned)f2bf(tile[r8 + 5][cc]) << 16);
            pk.w = (unsigned)f2bf(tile[r8 + 6][cc]) | ((unsigned)f2bf(tile[r8 + 7][cc]) << 16);
            *(uint4*)&outp[(size_t)(c0 + cc) * out_ld + out_off + r0 + r8] = pk;
        }
        return;
    }
    {   // pack_wdown: wdt[j][c] = wdown[e][c][r], j = e*16+r
        int idx = (b - 10584) * 256 + tid;
        int j = idx / 768, c = idx - j * 768;
        int e = j >> 4, r = j & 15;
        wdt[idx] = f2bf(wdn[((size_t)e * 768 + c) * 16 + r]);
    }
}

// ---- MFMA GEMM, C = A * Bt^T, TM x 128 tile, BK=32, LDS double-buffer --------
// TM=64: 128 thr, 2 waves (1x2).  TM=128: 256 thr, 4 waves (2x2).
// TM=256: 512 thr, 8 waves (4x2). Wave tile always 64x64 (acc 4x4).
// EPI 0: gelu(acc + b1[n]) -> bf16 Ap[m*3200 + n]
// EPI 1: wt[m, n>>4]*gelu(acc) -> bf16 Ap[m*3200 + 3072 + n]
// EPI 2: acc + b2[n] -> f32 out[m*768 + n]  (1-D grid + XCD swizzle)
// EPI 3: fused GEMM1+GEMMd: bx<24 -> EPI0 with Bt; bx==24 -> EPI1 with Bt2.

template <int EPI, int TM>
__global__ void __launch_bounds__(TM * 2)
gemm_bt_kernel(const unsigned short* __restrict__ A, int lda,
               const unsigned short* __restrict__ Bt, int ldb,
               int kIters,
               const float* __restrict__ bias,
               unsigned short* __restrict__ apOut,
               float* __restrict__ fOut,
               const int* __restrict__ tki,
               const float* __restrict__ tkp,
               const unsigned short* __restrict__ Bt2) {
    constexpr int NT    = TM * 2;          // threads
    constexpr int ABUF  = TM * 32;         // elems per A buffer
    constexpr int BBUF  = 128 * 32;        // elems per B buffer
    constexpr int BPASS = BBUF / (NT * 8); // staging passes for B tile
    __shared__ __align__(16) unsigned short As[2 * ABUF];
    __shared__ __align__(16) unsigned short Bs[2 * BBUF];

    int bx, by;
    if (EPI == 2) {
        // 1200 launched; same-by blocks share L&7 -> same XCD, consecutive.
        int L = blockIdx.x;
        int k = L & 7, t = L >> 3;
        bx = t % 6;
        by = (t / 6) * 8 + k;
        if (by >= NTOK / TM) return;       // block-uniform, pre-barrier safe
    } else {
        bx = blockIdx.x;
        by = blockIdx.y;
    }

    // Fused-launch B selection (block-uniform).
    const unsigned short* Bp = Bt;
    int n0 = bx * 128;
    if (EPI == 3 && bx == 24) { Bp = Bt2; n0 = 0; }

    const int tid  = threadIdx.x;
    const int wave = tid >> 6;
    const int lane = tid & 63;
    const int m0 = by * TM;
    const int wm = (wave >> 1) * 64;
    const int wn = (wave & 1) * 64;
    const int row16 = lane & 15;
    const int quad  = lane >> 4;
    const int kch   = quad * 8;

    f32x4 acc[4][4] = {};

    // Staging (proven layout): chunk ci covers a [rows][32] tile row-major
    // (row = ci>>2, kcol = (ci&3)*8); source contiguous in lane order; LDS
    // dest = wave-uniform base + lane*16B. 64-B row stride (2-bank, free).
    // A: always 2 passes of NT chunks (rows step NT/4). B: BPASS passes.
    const int r_s = tid >> 2;
    const int c_s = (tid & 3) * 8;
    const size_t aRow0 = (size_t)(m0 + r_s) * lda + c_s;
    const size_t bRow0 = (size_t)(n0 + r_s) * ldb + c_s;
    unsigned short* asBase = &As[wave * 512];
    unsigned short* bsBase = &Bs[wave * 512];

    // prologue: prefetch tile 0 into buffer 0
    #pragma unroll
    for (int p = 0; p < 2; ++p)
        __builtin_amdgcn_global_load_lds(GLOBAL_AS(A + aRow0 + (size_t)p * (NT / 4) * lda),
                                         LDS_AS(asBase + p * NT * 8), 16, 0, 0);
    #pragma unroll
    for (int p = 0; p < BPASS; ++p)
        __builtin_amdgcn_global_load_lds(GLOBAL_AS(Bp + bRow0 + (size_t)p * (NT / 4) * ldb),
                                         LDS_AS(bsBase + p * NT * 8), 16, 0, 0);

    for (int kt = 0; kt < kIters; ++kt) {
        // barrier: compiler-emitted vmcnt(0)+lgkmcnt(0) drain guarantees
        // buf[kt&1] landed AND all waves done reading buf[(kt+1)&1].
        __syncthreads();

        if (kt + 1 < kIters) {             // prefetch kt+1 into alternate buffer
            const int k1 = (kt + 1) * 32;
            const int pa = ((kt + 1) & 1) * ABUF;
            const int pb = ((kt + 1) & 1) * BBUF;
            #pragma unroll
            for (int p = 0; p < 2; ++p)
                __builtin_amdgcn_global_load_lds(GLOBAL_AS(A + aRow0 + k1 + (size_t)p * (NT / 4) * lda),
                                                 LDS_AS(asBase + pa + p * NT * 8), 16, 0, 0);
            #pragma unroll
            for (int p = 0; p < BPASS; ++p)
                __builtin_amdgcn_global_load_lds(GLOBAL_AS(Bp + bRow0 + k1 + (size_t)p * (NT / 4) * ldb),
                                                 LDS_AS(bsBase + pb + p * NT * 8), 16, 0, 0);
        }

        const int ca = (kt & 1) * ABUF;
        const int cb = (kt & 1) * BBUF;
        bf16x8 af[4], bfr[4];
        #pragma unroll
        for (int mi = 0; mi < 4; ++mi)
            af[mi] = *(const bf16x8*)&As[ca + (wm + mi * 16 + row16) * 32 + kch];
        #pragma unroll
        for (int ni = 0; ni < 4; ++ni)
            bfr[ni] = *(const bf16x8*)&Bs[cb + (wn + ni * 16 + row16) * 32 + kch];

        #pragma unroll
        for (int mi = 0; mi < 4; ++mi)
            #pragma unroll
            for (int ni = 0; ni < 4; ++ni)
                acc[mi][ni] = __builtin_amdgcn_mfma_f32_16x16x32_bf16(
                    af[mi], bfr[ni], acc[mi][ni], 0, 0, 0);
    }

    // epilogue (R8-exact): lane holds col = row16 (+16*ni), rows quad*4 + i
    const bool doLora = (EPI == 1) || (EPI == 3 && bx == 24);
    #pragma unroll
    for (int mi = 0; mi < 4; ++mi) {
        #pragma unroll
        for (int i = 0; i < 4; ++i) {
            const int m = m0 + wm + mi * 16 + quad * 4 + i;
            int i0 = 0, i1 = 0; float p0 = 0.f, p1 = 0.f;
            if (doLora) {
                i0 = tki[m * 2]; i1 = tki[m * 2 + 1];
                p0 = tkp[m * 2]; p1 = tkp[m * 2 + 1];
            }
            #pragma unroll
            for (int ni = 0; ni < 4; ++ni) {
                const int ncol = n0 + wn + ni * 16 + row16;
                float v = acc[mi][ni][i];
                if (EPI == 2) {
                    fOut[(size_t)m * CDIM + ncol] = v + bias[ncol];
                } else if (doLora) {
                    const int e = ncol >> 4;
                    float wt = (i0 == e ? p0 : 0.f) + (i1 == e ? p1 : 0.f);
                    v = gelu_fast(v) * wt;
                    apOut[(size_t)m * KBIG + 3072 + ncol] = f2bf(v);
                } else {
                    v = gelu_fast(v + bias[ncol]);
                    apOut[(size_t)m * KBIG + ncol] = f2bf(v);
                }
            }
        }
    }
}

// ---------------- launch ----------------

extern "C" void kernel_launch(void* const* d_in, const int* in_sizes, int n_in,
                              void* d_out, int out_size, void* d_ws, size_t ws_size,
                              hipStream_t stream) {
    const float* x   = (const float*)d_in[0];
    const float* tkp = (const float*)d_in[1];
    const int*   tki = (const int*)d_in[2];
    const float* w1  = (const float*)d_in[3];
    const float* b1  = (const float*)d_in[4];
    const float* w2  = (const float*)d_in[5];
    const float* b2  = (const float*)d_in[6];
    const float* wdn = (const float*)d_in[7];
    const float* wup = (const float*)d_in[8];
    float* out = (float*)d_out;

    unsigned short* xb  = (unsigned short*)d_ws;
    unsigned short* w1t = xb  + (size_t)NTOK * CDIM;      // 3072 x 768
    unsigned short* B2t = w1t + (size_t)HIDDIM * CDIM;    // 768 x 3200
    unsigned short* wdt = B2t + (size_t)CDIM * KBIG;      // 128 x 768
    unsigned short* Ap  = wdt + (size_t)128 * CDIM;       // 12544 x 3200

    prep_kernel<<<dim3(10968), 256, 0, stream>>>(x, w1, w2, wup, wdn,
                                                 xb, w1t, B2t, wdt);

    // Fused GEMM1 (bx<24: h -> Ap[:,0:3072]) + GEMMd (bx==24: sd -> Ap[:,3072:])
    // grid (25, 49), 512 threads, TM=256.
    gemm_bt_kernel<3, 256><<<dim3(25, NTOK / 256), 512, 0, stream>>>(
        xb, CDIM, w1t, CDIM, CDIM / 32, b1, Ap, nullptr, tki, tkp, wdt);
    // GEMM2: out = Ap @ B2t^T + b2 ; TM=64, 1200-block XCD-swizzled grid
    // (1176 useful = 4.6 blocks/CU, 24 KB LDS -> 6 resident = 12 waves/CU).
    gemm_bt_kernel<2, 64><<<dim3(1200), 128, 0, stream>>>(
        Ap, KBIG, B2t, KBIG, KBIG / 32, b2, nullptr, out, nullptr, nullptr, nullptr);
}

// Round 2
// 307.247 us; speedup vs baseline: 1.0657x; 1.0657x over previous
//
#include <hip/hip_runtime.h>
#include <hip/hip_bf16.h>
#include <math.h>

// ConvNeXt MLP + parallel MoE-LoRA, fp32 in/out, bf16-tolerance harness.
// B,H,W,C = 64,14,14,768 ; N_tok = 12544 = 98*128 ; HID = 3072 ; E=8,K=2,R=16.
//
//   h  = gelu(x @ w1 + b1)                GEMM1  [12544,768]x[768,3072]
//   sd = wt * gelu(x @ wdown)             GEMMd  [12544,768]x[768,128]
//   out = [h | sd] @ [w2 ; wup] + b2      GEMM2  [12544,3200]x[3200,768]
//
// R14: R13 post-mortem: (a) fused GEMM1 regressed (runtime-B codegen), (b)
// GEMM2 TM=64 doubled B staging (structure is staging-stream-bound ~9.9TB/s,
// not latency-bound). Revert GEMMd to separate R12 kernel; replace BOTH big
// GEMMs with the 8-phase 256x256 BK=64 schedule (T2 st_16x32 swizzle via
// pre-swizzled global source + swizzled ds_read, T3/T4 counted vmcnt(4)
// never 0 in main loop, T5 setprio around MFMA cluster). 128KB LDS, 8 waves
// (2Mx4N), per-wave 128x64 output. GEMM1 grid (12,49), GEMM2 grid (3,49).

#define NTOK   12544
#define CDIM   768
#define HIDDIM 3072
#define KBIG   3200

typedef __attribute__((ext_vector_type(8))) short bf16x8;
typedef __attribute__((ext_vector_type(4))) float f32x4;

#define GLOBAL_AS(p) ((const __attribute__((address_space(1))) void*)(p))
#define LDS_AS(p)    ((__attribute__((address_space(3))) void*)(p))
#define GLD(src, dst) __builtin_amdgcn_global_load_lds(GLOBAL_AS(src), LDS_AS(dst), 16, 0, 0)

__device__ inline unsigned short f2bf(float f) {
    unsigned int x = __float_as_uint(f);
    x += 0x7fffu + ((x >> 16) & 1u);   // RNE
    return (unsigned short)(x >> 16);
}

// tanh-form GELU, branch-free; max |err| ~4.3e-4 vs exact erf form.
__device__ inline float gelu_fast(float x) {
    float x3 = x * x * x;
    float u2 = 1.5957691216057308f * x + 0.07135481627260025f * x3;
    float e = __expf(-u2);
    return x * __builtin_amdgcn_rcpf(1.0f + e);
}

// ---------------- fused prep: cast_x + 3 transposes (64x64) + pack_wdown -------
__global__ void __launch_bounds__(256) prep_kernel(
        const float* __restrict__ x, const float* __restrict__ w1,
        const float* __restrict__ w2, const float* __restrict__ wup,
        const float* __restrict__ wdn,
        unsigned short* __restrict__ xb, unsigned short* __restrict__ w1t,
        unsigned short* __restrict__ B2t, unsigned short* __restrict__ wdt) {
    __shared__ float tile[64][65];
    const int b = blockIdx.x, tid = threadIdx.x;
    if (b < 9408) {                      // cast x -> bf16, float4->ushort4
        int i = b * 256 + tid;
        float4 v = ((const float4*)x)[i];
        ushort4 o;
        o.x = f2bf(v.x); o.y = f2bf(v.y); o.z = f2bf(v.z); o.w = f2bf(v.w);
        ((ushort4*)xb)[i] = o;
        return;
    }
    if (b < 10584) {                     // 64x64 transpose tiles
        const float* in; unsigned short* outp; int Ccols, out_ld, out_off, bx, by;
        if (b < 9984)       { int t = b - 9408;  in = w1;  outp = w1t; Ccols = 3072; out_ld = 768;  out_off = 0;    bx = t % 48; by = t / 48; }
        else if (b < 10560) { int t = b - 9984;  in = w2;  outp = B2t; Ccols = 768;  out_ld = 3200; out_off = 0;    bx = t % 12; by = t / 12; }
        else                { int t = b - 10560; in = wup; outp = B2t; Ccols = 768;  out_ld = 3200; out_off = 3072; bx = t % 12; by = t / 12; }
        const int c0 = bx * 64, r0 = by * 64;
        #pragma unroll
        for (int p = 0; p < 4; ++p) {
            int idx = p * 256 + tid;
            int r = idx >> 4, c4 = (idx & 15) * 4;
            float4 v = *(const float4*)&in[(size_t)(r0 + r) * Ccols + c0 + c4];
            tile[r][c4 + 0] = v.x; tile[r][c4 + 1] = v.y;
            tile[r][c4 + 2] = v.z; tile[r][c4 + 3] = v.w;
        }
        __syncthreads();
        #pragma unroll
        for (int p = 0; p < 2; ++p) {
            int u = p * 256 + tid;
            int cc = u >> 3, r8 = (u & 7) * 8;
            uint4 pk;
            pk.x = (unsigned)f2bf(tile[r8 + 0][cc]) | ((unsigned)f2bf(tile[r8 + 1][cc]) << 16);
            pk.y = (unsigned)f2bf(tile[r8 + 2][cc]) | ((unsigned)f2bf(tile[r8 + 3][cc]) << 16);
            pk.z = (unsigned)f2bf(tile[r8 + 4][cc]) | ((unsigned)f2bf(tile[r8 + 5][cc]) << 16);
            pk.w = (unsigned)f2bf(tile[r8 + 6][cc]) | ((unsigned)f2bf(tile[r8 + 7][cc]) << 16);
            *(uint4*)&outp[(size_t)(c0 + cc) * out_ld + out_off + r0 + r8] = pk;
        }
        return;
    }
    {   // pack_wdown: wdt[j][c] = wdown[e][c][r], j = e*16+r
        int idx = (b - 10584) * 256 + tid;
        int j = idx / 768, c = idx - j * 768;
        int e = j >> 4, r = j & 15;
        wdt[idx] = f2bf(wdn[((size_t)e * 768 + c) * 16 + r]);
    }
}

// ---- old MFMA GEMM (R12-proven), used only for GEMMd (EPI=1, TM=128) --------
template <int EPI, int TM>
__global__ void __launch_bounds__(TM * 2)
gemm_bt_kernel(const unsigned short* __restrict__ A, int lda,
               const unsigned short* __restrict__ Bt, int ldb,
               int kIters,
               const float* __restrict__ bias,
               unsigned short* __restrict__ apOut,
               float* __restrict__ fOut,
               const int* __restrict__ tki,
               const float* __restrict__ tkp) {
    constexpr int NT    = TM * 2;          // threads
    constexpr int ABUF  = TM * 32;         // elems per A buffer
    constexpr int BBUF  = 128 * 32;        // elems per B buffer
    __shared__ __align__(16) unsigned short As[2 * ABUF];
    __shared__ __align__(16) unsigned short Bs[2 * BBUF];

    const int bx = blockIdx.x, by = blockIdx.y;
    const int tid  = threadIdx.x;
    const int wave = tid >> 6;
    const int lane = tid & 63;
    const int m0 = by * TM;
    const int n0 = bx * 128;
    const int wm = (wave >> 1) * 64;
    const int wn = (wave & 1) * 64;
    const int row16 = lane & 15;
    const int quad  = lane >> 4;
    const int kch   = quad * 8;

    f32x4 acc[4][4] = {};

    const int r_s = tid >> 2;
    const int c_s = (tid & 3) * 8;
    const size_t aRow0 = (size_t)(m0 + r_s) * lda + c_s;
    const size_t aRow1 = aRow0 + (size_t)(NT / 4) * lda;
    const size_t bRow0 = (size_t)(n0 + r_s) * ldb + c_s;
    const size_t bRow1 = bRow0 + (size_t)64 * ldb;       // used only if TM==128
    unsigned short* asB0 = &As[(wave * 64) * 8];
    unsigned short* asB1 = &As[(NT + wave * 64) * 8];
    unsigned short* bsB0 = &Bs[(wave * 64) * 8];
    unsigned short* bsB1 = &Bs[(256 + wave * 64) * 8];

    {
        GLD(A + aRow0, asB0);
        GLD(A + aRow1, asB1);
        GLD(Bt + bRow0, bsB0);
        if (TM == 128) GLD(Bt + bRow1, bsB1);
    }

    for (int kt = 0; kt < kIters; ++kt) {
        __syncthreads();

        if (kt + 1 < kIters) {
            const int k1 = (kt + 1) * 32;
            const int pa = ((kt + 1) & 1) * ABUF;
            const int pb = ((kt + 1) & 1) * BBUF;
            GLD(A + aRow0 + k1, asB0 + pa);
            GLD(A + aRow1 + k1, asB1 + pa);
            GLD(Bt + bRow0 + k1, bsB0 + pb);
            if (TM == 128) GLD(Bt + bRow1 + k1, bsB1 + pb);
        }

        const int ca = (kt & 1) * ABUF;
        const int cb = (kt & 1) * BBUF;
        bf16x8 af[4], bfr[4];
        #pragma unroll
        for (int mi = 0; mi < 4; ++mi)
            af[mi] = *(const bf16x8*)&As[ca + (wm + mi * 16 + row16) * 32 + kch];
        #pragma unroll
        for (int ni = 0; ni < 4; ++ni)
            bfr[ni] = *(const bf16x8*)&Bs[cb + (wn + ni * 16 + row16) * 32 + kch];

        #pragma unroll
        for (int mi = 0; mi < 4; ++mi)
            #pragma unroll
            for (int ni = 0; ni < 4; ++ni)
                acc[mi][ni] = __builtin_amdgcn_mfma_f32_16x16x32_bf16(
                    af[mi], bfr[ni], acc[mi][ni], 0, 0, 0);
    }

    #pragma unroll
    for (int mi = 0; mi < 4; ++mi) {
        #pragma unroll
        for (int i = 0; i < 4; ++i) {
            const int m = m0 + wm + mi * 16 + quad * 4 + i;
            int i0 = 0, i1 = 0; float p0 = 0.f, p1 = 0.f;
            if (EPI == 1) {
                i0 = tki[m * 2]; i1 = tki[m * 2 + 1];
                p0 = tkp[m * 2]; p1 = tkp[m * 2 + 1];
            }
            #pragma unroll
            for (int ni = 0; ni < 4; ++ni) {
                const int ncol = n0 + wn + ni * 16 + row16;
                float v = acc[mi][ni][i];
                if (EPI == 0) {
                    v = gelu_fast(v + bias[ncol]);
                    apOut[(size_t)m * KBIG + ncol] = f2bf(v);
                } else if (EPI == 1) {
                    const int e = ncol >> 4;
                    float wt = (i0 == e ? p0 : 0.f) + (i1 == e ? p1 : 0.f);
                    v = gelu_fast(v) * wt;
                    apOut[(size_t)m * KBIG + 3072 + ncol] = f2bf(v);
                } else {
                    fOut[(size_t)m * CDIM + ncol] = v + bias[ncol];
                }
            }
        }
    }
}

// ---- 8-phase 256x256 BK=64 GEMM (T2+T3+T4+T5), C = A * Bt^T -----------------
// 512 thr = 8 waves (2M x 4N); per-wave C = 128x64 (acc[8][4] f32x4).
// LDS 128KB: A bufs [2]x32KB at 0, B bufs [2]x32KB at +64KB. K-tile = 64 cols;
// stored [256 rows][64 cols] row-major (128B rows), halves = rows 0-127/128-255.
// st_16x32 swizzle: byte ^= ((byte>>9)&1)<<5 — applied to the GLOBAL source
// address (LDS dest stays linear, rule #21) and to the ds_read address.
// Half-tile issue schedule (1 per phase; buffer free-window verified):
//   ph0: A0(t+1)  ph1: A1(t+1)  ph2: B0(t+2)  ph3: B1(t+2)  [vmcnt(4)]
//   ph4: A0(t+2)  ph5: A1(t+2)  ph6: B0(t+3)  ph7: B1(t+3)  [vmcnt(4)]
// vmcnt(4) leaves exactly the 2 newest half-tiles outstanding; everything the
// next 4 phases ds_read is forced landed. Never drains to 0 in the main loop.

template <int Q, bool TAILV, class Issue>
__device__ __forceinline__ void phase8(
        const char* ldsAbuf, const char* ldsBbuf, int aFB, int bFB,
        f32x4 (&acc)[8][4], bf16x8 (&bfr)[4][2], Issue issue) {
    bf16x8 af[2][2];
    #pragma unroll
    for (int f = 0; f < 2; ++f)
        #pragma unroll
        for (int k = 0; k < 2; ++k)
            af[f][k] = *(const bf16x8*)(ldsAbuf + aFB + Q * 4096 + f * 2048 + k * 64);
    if (Q == 0) {
        #pragma unroll
        for (int nf = 0; nf < 4; ++nf)
            #pragma unroll
            for (int k = 0; k < 2; ++k)
                bfr[nf][k] = *(const bf16x8*)(ldsBbuf + bFB + nf * 2048 + k * 64);
    }
    issue();
    __builtin_amdgcn_s_barrier();
    asm volatile("s_waitcnt lgkmcnt(0)" ::: "memory");
    __builtin_amdgcn_sched_barrier(0);
    __builtin_amdgcn_s_setprio(1);
    #pragma unroll
    for (int f = 0; f < 2; ++f)
        #pragma unroll
        for (int nf = 0; nf < 4; ++nf)
            #pragma unroll
            for (int k = 0; k < 2; ++k)
                acc[2 * Q + f][nf] = __builtin_amdgcn_mfma_f32_16x16x32_bf16(
                    af[f][k], bfr[nf][k], acc[2 * Q + f][nf], 0, 0, 0);
    __builtin_amdgcn_s_setprio(0);
    if (TAILV) asm volatile("s_waitcnt vmcnt(4)" ::: "memory");
    __builtin_amdgcn_s_barrier();
    __builtin_amdgcn_sched_barrier(0);
}

// EPI 0: gelu(acc + bias[n]) -> bf16 apOut[m*3200 + n]   (GEMM1)
// EPI 2: acc + bias[n]       -> f32  fOut[m*768 + n]     (GEMM2)
template <int EPI>
__global__ void __launch_bounds__(512, 2)
gemm8_kernel(const unsigned short* __restrict__ A, int lda,
             const unsigned short* __restrict__ Bt, int ldb,
             int kTiles, const float* __restrict__ bias,
             unsigned short* __restrict__ apOut, float* __restrict__ fOut) {
    __shared__ __align__(1024) unsigned short ldsbuf[65536];   // 128 KiB
    char* ldsA = (char*)ldsbuf;
    char* ldsB = (char*)ldsbuf + 65536;

    const int tid  = threadIdx.x;
    const int wave = tid >> 6;
    const int lane = tid & 63;
    const int m0 = blockIdx.y * 256;
    const int n0 = blockIdx.x * 256;
    const int row16 = lane & 15;
    const int quad  = lane >> 4;
    const int wm = (wave >> 2) << 7;      // 0 / 128
    const int wn = (wave & 3) << 6;       // 0 / 64 / 128 / 192
    // ds_read fragment base, swizzled (bit9 of logical offset == (row16>>2)&1)
    const int swz = ((row16 >> 2) & 1) << 5;
    const int aFB = (((wm + row16) << 7) + (quad << 4)) ^ swz;
    const int bFB = (((wn + row16) << 7) + (quad << 4)) ^ swz;

    // staging: dest linear in tid (dest = wavebase + lane*16); source address
    // pre-swizzled with the same involution so LDS content is swizzle-stored.
    const int d  = tid << 4;
    const int s  = d ^ (((d >> 9) & 1) << 5);
    const int sr = s >> 7;                // source row 0..63 (per pass)
    const int sc = (s & 127) >> 1;        // source col elem (16B chunk)
    const char* aSrc = (const char*)(A + (size_t)(m0 + sr) * lda + sc);
    const char* bSrc = (const char*)(Bt + (size_t)(n0 + sr) * ldb + sc);
    const size_t aPass = (size_t)64 * lda * 2, aHalf = aPass * 2;
    const size_t bPass = (size_t)64 * ldb * 2, bHalf = bPass * 2;
    const int ldsW = wave << 10;

    auto issueA = [&](int b, int h, int tk) {
        const char* sp = aSrc + (size_t)h * aHalf + (size_t)tk * 128;
        char* dp = ldsA + b * 32768 + h * 16384 + ldsW;
        GLD(sp, dp);
        GLD(sp + aPass, dp + 8192);
    };
    auto issueB = [&](int b, int h, int tk) {
        const char* sp = bSrc + (size_t)h * bHalf + (size_t)tk * 128;
        char* dp = ldsB + b * 32768 + h * 16384 + ldsW;
        GLD(sp, dp);
        GLD(sp + bPass, dp + 8192);
    };

    f32x4 acc[8][4] = {};

    // prologue: B(0)->bufB0, A(0)->bufA0, B(1)->bufB1; allow B(1) outstanding
    issueB(0, 0, 0); issueB(0, 1, 0);
    issueA(0, 0, 0); issueA(0, 1, 0);
    issueB(1, 0, 1); issueB(1, 1, 1);
    asm volatile("s_waitcnt vmcnt(4)" ::: "memory");
    __builtin_amdgcn_s_barrier();
    __builtin_amdgcn_sched_barrier(0);

    const char* A0 = ldsA;         const char* B0 = ldsB;
    const char* A1 = ldsA + 32768; const char* B1 = ldsB + 32768;
    const int nIter = kTiles >> 1;
    for (int it = 0; it < nIter; ++it) {
        const int t  = it * 2;
        const int t2 = (t + 2 < kTiles) ? t + 2 : 0;   // clamped (harmless re-stage)
        const int t3 = (t + 3 < kTiles) ? t + 3 : 0;
        bf16x8 bfr[4][2];
        phase8<0, false>(A0, B0, aFB, bFB, acc, bfr, [&]{ issueA(1, 0, t + 1); });
        phase8<1, false>(A0, B0, aFB, bFB, acc, bfr, [&]{ issueA(1, 1, t + 1); });
        phase8<2, false>(A0, B0, aFB, bFB, acc, bfr, [&]{ issueB(0, 0, t2); });
        phase8<3, true >(A0, B0, aFB, bFB, acc, bfr, [&]{ issueB(0, 1, t2); });
        phase8<0, false>(A1, B1, aFB, bFB, acc, bfr, [&]{ issueA(0, 0, t2); });
        phase8<1, false>(A1, B1, aFB, bFB, acc, bfr, [&]{ issueA(0, 1, t2); });
        phase8<2, false>(A1, B1, aFB, bFB, acc, bfr, [&]{ issueB(1, 0, t3); });
        phase8<3, true >(A1, B1, aFB, bFB, acc, bfr, [&]{ issueB(1, 1, t3); });
    }
    asm volatile("s_waitcnt vmcnt(0)" ::: "memory");

    // epilogue: C/D layout col = row16 + nf*16, row = quad*4 + i (+ mi*16)
    float bv[4];
    #pragma unroll
    for (int nf = 0; nf < 4; ++nf) bv[nf] = bias[n0 + wn + nf * 16 + row16];
    #pragma unroll
    for (int mi = 0; mi < 8; ++mi) {
        #pragma unroll
        for (int i = 0; i < 4; ++i) {
            const int m = m0 + wm + mi * 16 + quad * 4 + i;
            #pragma unroll
            for (int nf = 0; nf < 4; ++nf) {
                const int col = n0 + wn + nf * 16 + row16;
                float v = acc[mi][nf][i] + bv[nf];
                if (EPI == 0) apOut[(size_t)m * KBIG + col] = f2bf(gelu_fast(v));
                else          fOut[(size_t)m * CDIM + col] = v;
            }
        }
    }
}

// ---------------- launch ----------------

extern "C" void kernel_launch(void* const* d_in, const int* in_sizes, int n_in,
                              void* d_out, int out_size, void* d_ws, size_t ws_size,
                              hipStream_t stream) {
    const float* x   = (const float*)d_in[0];
    const float* tkp = (const float*)d_in[1];
    const int*   tki = (const int*)d_in[2];
    const float* w1  = (const float*)d_in[3];
    const float* b1  = (const float*)d_in[4];
    const float* w2  = (const float*)d_in[5];
    const float* b2  = (const float*)d_in[6];
    const float* wdn = (const float*)d_in[7];
    const float* wup = (const float*)d_in[8];
    float* out = (float*)d_out;

    unsigned short* xb  = (unsigned short*)d_ws;
    unsigned short* w1t = xb  + (size_t)NTOK * CDIM;      // 3072 x 768
    unsigned short* B2t = w1t + (size_t)HIDDIM * CDIM;    // 768 x 3200
    unsigned short* wdt = B2t + (size_t)CDIM * KBIG;      // 128 x 768
    unsigned short* Ap  = wdt + (size_t)128 * CDIM;       // 12544 x 3200

    prep_kernel<<<dim3(10968), 256, 0, stream>>>(x, w1, w2, wup, wdn,
                                                 xb, w1t, B2t, wdt);

    // GEMMd: sd -> Ap[:, 3072:3200] ; 98 blocks, proven R12 kernel
    gemm_bt_kernel<1, 128><<<dim3(1, NTOK / 128), 256, 0, stream>>>(
        xb, CDIM, wdt, CDIM, CDIM / 32, nullptr, Ap, nullptr, tki, tkp);
    // GEMM1: h -> Ap[:, 0:3072] ; 8-phase 256x256, grid (12,49), kTiles=12
    gemm8_kernel<0><<<dim3(HIDDIM / 256, NTOK / 256), 512, 0, stream>>>(
        xb, CDIM, w1t, CDIM, CDIM / 64, b1, Ap, nullptr);
    // GEMM2: out = Ap @ B2t^T + b2 ; 8-phase 256x256, grid (3,49), kTiles=50
    gemm8_kernel<2><<<dim3(CDIM / 256, NTOK / 256), 512, 0, stream>>>(
        Ap, KBIG, B2t, KBIG, KBIG / 64, b2, nullptr, out);
}

// Round 3
// 286.323 us; speedup vs baseline: 1.1436x; 1.0731x over previous
//
#include <hip/hip_runtime.h>
#include <hip/hip_bf16.h>
#include <math.h>

// ConvNeXt MLP + parallel MoE-LoRA, fp32 in/out, bf16-tolerance harness.
// B,H,W,C = 64,14,14,768 ; N_tok = 12544 = 98*128 ; HID = 3072 ; E=8,K=2,R=16.
//
//   h  = gelu(x @ w1 + b1)                GEMM1  [12544,768]x[768,3072]
//   sd = wt * gelu(x @ wdown)             GEMMd  [12544,768]x[768,128]
//   out = [h | sd] @ [w2 ; wup] + b2      GEMM2  [12544,3200]x[3200,768]
//
// R15 = R14 + swizzle upgrade. R14 post-mortem: 8-phase structure landed
// (passed, GEMM2 96us) but SQ_LDS_BANK_CONFLICT=5.6M on GEMM2 (~4 extra
// cyc/ds_read on the lgkmcnt(0)-gated critical path): the 1-bit st_16x32
// XOR only spreads a 16-row column read across 2 slots (8-way residual).
// Fix: 3-bit XOR  byte ^= ((byte>>7)&7)<<4  (the G4-measured conflict-free
// pattern for 128B-row column reads) applied to BOTH sides of the
// involution: pre-swizzled global staging source + swizzled ds_read addr.
// XOR bits 4-6 disjoint from condition bits (>=7) -> valid involution;
// k*64 folded into the linear offset BEFORE the XOR.

#define NTOK   12544
#define CDIM   768
#define HIDDIM 3072
#define KBIG   3200

typedef __attribute__((ext_vector_type(8))) short bf16x8;
typedef __attribute__((ext_vector_type(4))) float f32x4;

#define GLOBAL_AS(p) ((const __attribute__((address_space(1))) void*)(p))
#define LDS_AS(p)    ((__attribute__((address_space(3))) void*)(p))
#define GLD(src, dst) __builtin_amdgcn_global_load_lds(GLOBAL_AS(src), LDS_AS(dst), 16, 0, 0)

__device__ inline unsigned short f2bf(float f) {
    unsigned int x = __float_as_uint(f);
    x += 0x7fffu + ((x >> 16) & 1u);   // RNE
    return (unsigned short)(x >> 16);
}

// tanh-form GELU, branch-free; max |err| ~4.3e-4 vs exact erf form.
__device__ inline float gelu_fast(float x) {
    float x3 = x * x * x;
    float u2 = 1.5957691216057308f * x + 0.07135481627260025f * x3;
    float e = __expf(-u2);
    return x * __builtin_amdgcn_rcpf(1.0f + e);
}

// ---------------- fused prep: cast_x + 3 transposes (64x64) + pack_wdown -------
__global__ void __launch_bounds__(256) prep_kernel(
        const float* __restrict__ x, const float* __restrict__ w1,
        const float* __restrict__ w2, const float* __restrict__ wup,
        const float* __restrict__ wdn,
        unsigned short* __restrict__ xb, unsigned short* __restrict__ w1t,
        unsigned short* __restrict__ B2t, unsigned short* __restrict__ wdt) {
    __shared__ float tile[64][65];
    const int b = blockIdx.x, tid = threadIdx.x;
    if (b < 9408) {                      // cast x -> bf16, float4->ushort4
        int i = b * 256 + tid;
        float4 v = ((const float4*)x)[i];
        ushort4 o;
        o.x = f2bf(v.x); o.y = f2bf(v.y); o.z = f2bf(v.z); o.w = f2bf(v.w);
        ((ushort4*)xb)[i] = o;
        return;
    }
    if (b < 10584) {                     // 64x64 transpose tiles
        const float* in; unsigned short* outp; int Ccols, out_ld, out_off, bx, by;
        if (b < 9984)       { int t = b - 9408;  in = w1;  outp = w1t; Ccols = 3072; out_ld = 768;  out_off = 0;    bx = t % 48; by = t / 48; }
        else if (b < 10560) { int t = b - 9984;  in = w2;  outp = B2t; Ccols = 768;  out_ld = 3200; out_off = 0;    bx = t % 12; by = t / 12; }
        else                { int t = b - 10560; in = wup; outp = B2t; Ccols = 768;  out_ld = 3200; out_off = 3072; bx = t % 12; by = t / 12; }
        const int c0 = bx * 64, r0 = by * 64;
        #pragma unroll
        for (int p = 0; p < 4; ++p) {
            int idx = p * 256 + tid;
            int r = idx >> 4, c4 = (idx & 15) * 4;
            float4 v = *(const float4*)&in[(size_t)(r0 + r) * Ccols + c0 + c4];
            tile[r][c4 + 0] = v.x; tile[r][c4 + 1] = v.y;
            tile[r][c4 + 2] = v.z; tile[r][c4 + 3] = v.w;
        }
        __syncthreads();
        #pragma unroll
        for (int p = 0; p < 2; ++p) {
            int u = p * 256 + tid;
            int cc = u >> 3, r8 = (u & 7) * 8;
            uint4 pk;
            pk.x = (unsigned)f2bf(tile[r8 + 0][cc]) | ((unsigned)f2bf(tile[r8 + 1][cc]) << 16);
            pk.y = (unsigned)f2bf(tile[r8 + 2][cc]) | ((unsigned)f2bf(tile[r8 + 3][cc]) << 16);
            pk.z = (unsigned)f2bf(tile[r8 + 4][cc]) | ((unsigned)f2bf(tile[r8 + 5][cc]) << 16);
            pk.w = (unsigned)f2bf(tile[r8 + 6][cc]) | ((unsigned)f2bf(tile[r8 + 7][cc]) << 16);
            *(uint4*)&outp[(size_t)(c0 + cc) * out_ld + out_off + r0 + r8] = pk;
        }
        return;
    }
    {   // pack_wdown: wdt[j][c] = wdown[e][c][r], j = e*16+r
        int idx = (b - 10584) * 256 + tid;
        int j = idx / 768, c = idx - j * 768;
        int e = j >> 4, r = j & 15;
        wdt[idx] = f2bf(wdn[((size_t)e * 768 + c) * 16 + r]);
    }
}

// ---- old MFMA GEMM (R12-proven), used only for GEMMd (EPI=1, TM=128) --------
template <int EPI, int TM>
__global__ void __launch_bounds__(TM * 2)
gemm_bt_kernel(const unsigned short* __restrict__ A, int lda,
               const unsigned short* __restrict__ Bt, int ldb,
               int kIters,
               const float* __restrict__ bias,
               unsigned short* __restrict__ apOut,
               float* __restrict__ fOut,
               const int* __restrict__ tki,
               const float* __restrict__ tkp) {
    constexpr int NT    = TM * 2;          // threads
    constexpr int ABUF  = TM * 32;         // elems per A buffer
    constexpr int BBUF  = 128 * 32;        // elems per B buffer
    __shared__ __align__(16) unsigned short As[2 * ABUF];
    __shared__ __align__(16) unsigned short Bs[2 * BBUF];

    const int bx = blockIdx.x, by = blockIdx.y;
    const int tid  = threadIdx.x;
    const int wave = tid >> 6;
    const int lane = tid & 63;
    const int m0 = by * TM;
    const int n0 = bx * 128;
    const int wm = (wave >> 1) * 64;
    const int wn = (wave & 1) * 64;
    const int row16 = lane & 15;
    const int quad  = lane >> 4;
    const int kch   = quad * 8;

    f32x4 acc[4][4] = {};

    const int r_s = tid >> 2;
    const int c_s = (tid & 3) * 8;
    const size_t aRow0 = (size_t)(m0 + r_s) * lda + c_s;
    const size_t aRow1 = aRow0 + (size_t)(NT / 4) * lda;
    const size_t bRow0 = (size_t)(n0 + r_s) * ldb + c_s;
    const size_t bRow1 = bRow0 + (size_t)64 * ldb;       // used only if TM==128
    unsigned short* asB0 = &As[(wave * 64) * 8];
    unsigned short* asB1 = &As[(NT + wave * 64) * 8];
    unsigned short* bsB0 = &Bs[(wave * 64) * 8];
    unsigned short* bsB1 = &Bs[(256 + wave * 64) * 8];

    {
        GLD(A + aRow0, asB0);
        GLD(A + aRow1, asB1);
        GLD(Bt + bRow0, bsB0);
        if (TM == 128) GLD(Bt + bRow1, bsB1);
    }

    for (int kt = 0; kt < kIters; ++kt) {
        __syncthreads();

        if (kt + 1 < kIters) {
            const int k1 = (kt + 1) * 32;
            const int pa = ((kt + 1) & 1) * ABUF;
            const int pb = ((kt + 1) & 1) * BBUF;
            GLD(A + aRow0 + k1, asB0 + pa);
            GLD(A + aRow1 + k1, asB1 + pa);
            GLD(Bt + bRow0 + k1, bsB0 + pb);
            if (TM == 128) GLD(Bt + bRow1 + k1, bsB1 + pb);
        }

        const int ca = (kt & 1) * ABUF;
        const int cb = (kt & 1) * BBUF;
        bf16x8 af[4], bfr[4];
        #pragma unroll
        for (int mi = 0; mi < 4; ++mi)
            af[mi] = *(const bf16x8*)&As[ca + (wm + mi * 16 + row16) * 32 + kch];
        #pragma unroll
        for (int ni = 0; ni < 4; ++ni)
            bfr[ni] = *(const bf16x8*)&Bs[cb + (wn + ni * 16 + row16) * 32 + kch];

        #pragma unroll
        for (int mi = 0; mi < 4; ++mi)
            #pragma unroll
            for (int ni = 0; ni < 4; ++ni)
                acc[mi][ni] = __builtin_amdgcn_mfma_f32_16x16x32_bf16(
                    af[mi], bfr[ni], acc[mi][ni], 0, 0, 0);
    }

    #pragma unroll
    for (int mi = 0; mi < 4; ++mi) {
        #pragma unroll
        for (int i = 0; i < 4; ++i) {
            const int m = m0 + wm + mi * 16 + quad * 4 + i;
            int i0 = 0, i1 = 0; float p0 = 0.f, p1 = 0.f;
            if (EPI == 1) {
                i0 = tki[m * 2]; i1 = tki[m * 2 + 1];
                p0 = tkp[m * 2]; p1 = tkp[m * 2 + 1];
            }
            #pragma unroll
            for (int ni = 0; ni < 4; ++ni) {
                const int ncol = n0 + wn + ni * 16 + row16;
                float v = acc[mi][ni][i];
                if (EPI == 0) {
                    v = gelu_fast(v + bias[ncol]);
                    apOut[(size_t)m * KBIG + ncol] = f2bf(v);
                } else if (EPI == 1) {
                    const int e = ncol >> 4;
                    float wt = (i0 == e ? p0 : 0.f) + (i1 == e ? p1 : 0.f);
                    v = gelu_fast(v) * wt;
                    apOut[(size_t)m * KBIG + 3072 + ncol] = f2bf(v);
                } else {
                    fOut[(size_t)m * CDIM + ncol] = v + bias[ncol];
                }
            }
        }
    }
}

// ---- 8-phase 256x256 BK=64 GEMM (T2+T3+T4+T5), C = A * Bt^T -----------------
// 512 thr = 8 waves (2M x 4N); per-wave C = 128x64 (acc[8][4] f32x4).
// LDS 128KB: A bufs [2]x32KB at 0, B bufs [2]x32KB at +64KB. K-tile = 64 cols;
// stored [256 rows][64 cols] row-major (128B rows), halves = rows 0-127/128-255.
// 3-bit swizzle: byte ^= ((byte>>7)&7)<<4  (16B slot index ^= row&7) —
// applied to the GLOBAL source address (LDS dest stays linear, rule #21) and
// to the fully-summed ds_read offset. A 16-row column read then covers all 8
// slots (32 banks), 2 lanes/slot = free.
// Half-tile issue schedule (1 per phase; buffer free-window verified):
//   ph0: A0(t+1)  ph1: A1(t+1)  ph2: B0(t+2)  ph3: B1(t+2)  [vmcnt(4)]
//   ph4: A0(t+2)  ph5: A1(t+2)  ph6: B0(t+3)  ph7: B1(t+3)  [vmcnt(4)]
// vmcnt(4) leaves exactly the 2 newest half-tiles outstanding; everything the
// next 4 phases ds_read is forced landed. Never drains to 0 in the main loop.

template <int Q, bool TAILV, class Issue>
__device__ __forceinline__ void phase8(
        const char* ldsAbuf, const char* ldsBbuf, int aFB, int bFB, int swz,
        f32x4 (&acc)[8][4], bf16x8 (&bfr)[4][2], Issue issue) {
    bf16x8 af[2][2];
    #pragma unroll
    for (int f = 0; f < 2; ++f)
        #pragma unroll
        for (int k = 0; k < 2; ++k)
            af[f][k] = *(const bf16x8*)(ldsAbuf + ((aFB + Q * 4096 + f * 2048 + k * 64) ^ swz));
    if (Q == 0) {
        #pragma unroll
        for (int nf = 0; nf < 4; ++nf)
            #pragma unroll
            for (int k = 0; k < 2; ++k)
                bfr[nf][k] = *(const bf16x8*)(ldsBbuf + ((bFB + nf * 2048 + k * 64) ^ swz));
    }
    issue();
    __builtin_amdgcn_s_barrier();
    asm volatile("s_waitcnt lgkmcnt(0)" ::: "memory");
    __builtin_amdgcn_sched_barrier(0);
    __builtin_amdgcn_s_setprio(1);
    #pragma unroll
    for (int f = 0; f < 2; ++f)
        #pragma unroll
        for (int nf = 0; nf < 4; ++nf)
            #pragma unroll
            for (int k = 0; k < 2; ++k)
                acc[2 * Q + f][nf] = __builtin_amdgcn_mfma_f32_16x16x32_bf16(
                    af[f][k], bfr[nf][k], acc[2 * Q + f][nf], 0, 0, 0);
    __builtin_amdgcn_s_setprio(0);
    if (TAILV) asm volatile("s_waitcnt vmcnt(4)" ::: "memory");
    __builtin_amdgcn_s_barrier();
    __builtin_amdgcn_sched_barrier(0);
}

// EPI 0: gelu(acc + bias[n]) -> bf16 apOut[m*3200 + n]   (GEMM1)
// EPI 2: acc + bias[n]       -> f32  fOut[m*768 + n]     (GEMM2)
template <int EPI>
__global__ void __launch_bounds__(512, 2)
gemm8_kernel(const unsigned short* __restrict__ A, int lda,
             const unsigned short* __restrict__ Bt, int ldb,
             int kTiles, const float* __restrict__ bias,
             unsigned short* __restrict__ apOut, float* __restrict__ fOut) {
    __shared__ __align__(1024) unsigned short ldsbuf[65536];   // 128 KiB
    char* ldsA = (char*)ldsbuf;
    char* ldsB = (char*)ldsbuf + 65536;

    const int tid  = threadIdx.x;
    const int wave = tid >> 6;
    const int lane = tid & 63;
    const int m0 = blockIdx.y * 256;
    const int n0 = blockIdx.x * 256;
    const int row16 = lane & 15;
    const int quad  = lane >> 4;
    const int wm = (wave >> 2) << 7;      // 0 / 128
    const int wn = (wave & 3) << 6;       // 0 / 64 / 128 / 192
    // ds_read fragment bases (UNswizzled); XOR applied to fully-summed offset.
    const int swz = (row16 & 7) << 4;
    const int aFB = ((wm + row16) << 7) + (quad << 4);
    const int bFB = ((wn + row16) << 7) + (quad << 4);

    // staging: dest linear in tid (dest = wavebase + lane*16); source address
    // pre-swizzled with the same involution so LDS content is swizzle-stored.
    const int d  = tid << 4;
    const int s  = d ^ (((d >> 7) & 7) << 4);
    const int sr = s >> 7;                // source row 0..63 (per pass)
    const int sc = (s & 127) >> 1;        // source col elem (16B chunk)
    const char* aSrc = (const char*)(A + (size_t)(m0 + sr) * lda + sc);
    const char* bSrc = (const char*)(Bt + (size_t)(n0 + sr) * ldb + sc);
    const size_t aPass = (size_t)64 * lda * 2, aHalf = aPass * 2;
    const size_t bPass = (size_t)64 * ldb * 2, bHalf = bPass * 2;
    const int ldsW = wave << 10;

    auto issueA = [&](int b, int h, int tk) {
        const char* sp = aSrc + (size_t)h * aHalf + (size_t)tk * 128;
        char* dp = ldsA + b * 32768 + h * 16384 + ldsW;
        GLD(sp, dp);
        GLD(sp + aPass, dp + 8192);
    };
    auto issueB = [&](int b, int h, int tk) {
        const char* sp = bSrc + (size_t)h * bHalf + (size_t)tk * 128;
        char* dp = ldsB + b * 32768 + h * 16384 + ldsW;
        GLD(sp, dp);
        GLD(sp + bPass, dp + 8192);
    };

    f32x4 acc[8][4] = {};

    // prologue: B(0)->bufB0, A(0)->bufA0, B(1)->bufB1; allow B(1) outstanding
    issueB(0, 0, 0); issueB(0, 1, 0);
    issueA(0, 0, 0); issueA(0, 1, 0);
    issueB(1, 0, 1); issueB(1, 1, 1);
    asm volatile("s_waitcnt vmcnt(4)" ::: "memory");
    __builtin_amdgcn_s_barrier();
    __builtin_amdgcn_sched_barrier(0);

    const char* A0 = ldsA;         const char* B0 = ldsB;
    const char* A1 = ldsA + 32768; const char* B1 = ldsB + 32768;
    const int nIter = kTiles >> 1;
    for (int it = 0; it < nIter; ++it) {
        const int t  = it * 2;
        const int t2 = (t + 2 < kTiles) ? t + 2 : 0;   // clamped (harmless re-stage)
        const int t3 = (t + 3 < kTiles) ? t + 3 : 0;
        bf16x8 bfr[4][2];
        phase8<0, false>(A0, B0, aFB, bFB, swz, acc, bfr, [&]{ issueA(1, 0, t + 1); });
        phase8<1, false>(A0, B0, aFB, bFB, swz, acc, bfr, [&]{ issueA(1, 1, t + 1); });
        phase8<2, false>(A0, B0, aFB, bFB, swz, acc, bfr, [&]{ issueB(0, 0, t2); });
        phase8<3, true >(A0, B0, aFB, bFB, swz, acc, bfr, [&]{ issueB(0, 1, t2); });
        phase8<0, false>(A1, B1, aFB, bFB, swz, acc, bfr, [&]{ issueA(0, 0, t2); });
        phase8<1, false>(A1, B1, aFB, bFB, swz, acc, bfr, [&]{ issueA(0, 1, t2); });
        phase8<2, false>(A1, B1, aFB, bFB, swz, acc, bfr, [&]{ issueB(1, 0, t3); });
        phase8<3, true >(A1, B1, aFB, bFB, swz, acc, bfr, [&]{ issueB(1, 1, t3); });
    }
    asm volatile("s_waitcnt vmcnt(0)" ::: "memory");

    // epilogue: C/D layout col = row16 + nf*16, row = quad*4 + i (+ mi*16)
    float bv[4];
    #pragma unroll
    for (int nf = 0; nf < 4; ++nf) bv[nf] = bias[n0 + wn + nf * 16 + row16];
    #pragma unroll
    for (int mi = 0; mi < 8; ++mi) {
        #pragma unroll
        for (int i = 0; i < 4; ++i) {
            const int m = m0 + wm + mi * 16 + quad * 4 + i;
            #pragma unroll
            for (int nf = 0; nf < 4; ++nf) {
                const int col = n0 + wn + nf * 16 + row16;
                float v = acc[mi][nf][i] + bv[nf];
                if (EPI == 0) apOut[(size_t)m * KBIG + col] = f2bf(gelu_fast(v));
                else          fOut[(size_t)m * CDIM + col] = v;
            }
        }
    }
}

// ---------------- launch ----------------

extern "C" void kernel_launch(void* const* d_in, const int* in_sizes, int n_in,
                              void* d_out, int out_size, void* d_ws, size_t ws_size,
                              hipStream_t stream) {
    const float* x   = (const float*)d_in[0];
    const float* tkp = (const float*)d_in[1];
    const int*   tki = (const int*)d_in[2];
    const float* w1  = (const float*)d_in[3];
    const float* b1  = (const float*)d_in[4];
    const float* w2  = (const float*)d_in[5];
    const float* b2  = (const float*)d_in[6];
    const float* wdn = (const float*)d_in[7];
    const float* wup = (const float*)d_in[8];
    float* out = (float*)d_out;

    unsigned short* xb  = (unsigned short*)d_ws;
    unsigned short* w1t = xb  + (size_t)NTOK * CDIM;      // 3072 x 768
    unsigned short* B2t = w1t + (size_t)HIDDIM * CDIM;    // 768 x 3200
    unsigned short* wdt = B2t + (size_t)CDIM * KBIG;      // 128 x 768
    unsigned short* Ap  = wdt + (size_t)128 * CDIM;       // 12544 x 3200

    prep_kernel<<<dim3(10968), 256, 0, stream>>>(x, w1, w2, wup, wdn,
                                                 xb, w1t, B2t, wdt);

    // GEMMd: sd -> Ap[:, 3072:3200] ; 98 blocks, proven R12 kernel
    gemm_bt_kernel<1, 128><<<dim3(1, NTOK / 128), 256, 0, stream>>>(
        xb, CDIM, wdt, CDIM, CDIM / 32, nullptr, Ap, nullptr, tki, tkp);
    // GEMM1: h -> Ap[:, 0:3072] ; 8-phase 256x256, grid (12,49), kTiles=12
    gemm8_kernel<0><<<dim3(HIDDIM / 256, NTOK / 256), 512, 0, stream>>>(
        xb, CDIM, w1t, CDIM, CDIM / 64, b1, Ap, nullptr);
    // GEMM2: out = Ap @ B2t^T + b2 ; 8-phase 256x256, grid (3,49), kTiles=50
    gemm8_kernel<2><<<dim3(CDIM / 256, NTOK / 256), 512, 0, stream>>>(
        Ap, KBIG, B2t, KBIG, KBIG / 64, b2, nullptr, out);
}

// Round 4
// 271.741 us; speedup vs baseline: 1.2050x; 1.0537x over previous
//
#include <hip/hip_runtime.h>
#include <hip/hip_bf16.h>
#include <math.h>

// ConvNeXt MLP + parallel MoE-LoRA, fp32 in/out, bf16-tolerance harness.
// B,H,W,C = 64,14,14,768 ; N_tok = 12544 = 98*128 ; HID = 3072 ; E=8,K=2,R=16.
//
//   h  = gelu(x @ w1 + b1)                GEMM1  [12544,768]x[768,3072]
//   sd = wt * gelu(x @ wdown)             GEMMd  [12544,768]x[768,128]
//   out = [h | sd] @ [w2 ; wup] + b2      GEMM2  [12544,3200]x[3200,768]
//
// R16 = R15 (3-bit swizzle: conflicts 5.6M -> 0, 307 -> 286) + two fixes:
//   1. GEMM2 N-tile 192 (NFRAG=3 template): grid 196 blocks -> CU coverage
//      57% -> 77%, LDS 112KB. B staged as NFRAG x 8KB chunks; vmcnt tails
//      re-derived: outstanding = ph2(2)+ph3(NFRAG-2) = NFRAG -> vmcnt(3).
//   2. Bijective XCD swizzle (m204 formula; 588%8=4, 196%8=4 so the naive
//      %8 remap is non-bijective) on both gemm8 grids, bx-fast chunks: each
//      XCD's contiguous wgid chunk shares A row-panels -> A fetched ~1x per
//      XCD instead of 8x (GEMM1 FETCH 97MB -> ~40MB, less L2-miss latency
//      exposed at the vmcnt waits).

#define NTOK   12544
#define CDIM   768
#define HIDDIM 3072
#define KBIG   3200

typedef __attribute__((ext_vector_type(8))) short bf16x8;
typedef __attribute__((ext_vector_type(4))) float f32x4;

#define GLOBAL_AS(p) ((const __attribute__((address_space(1))) void*)(p))
#define LDS_AS(p)    ((__attribute__((address_space(3))) void*)(p))
#define GLD(src, dst) __builtin_amdgcn_global_load_lds(GLOBAL_AS(src), LDS_AS(dst), 16, 0, 0)

__device__ inline unsigned short f2bf(float f) {
    unsigned int x = __float_as_uint(f);
    x += 0x7fffu + ((x >> 16) & 1u);   // RNE
    return (unsigned short)(x >> 16);
}

// tanh-form GELU, branch-free; max |err| ~4.3e-4 vs exact erf form.
__device__ inline float gelu_fast(float x) {
    float x3 = x * x * x;
    float u2 = 1.5957691216057308f * x + 0.07135481627260025f * x3;
    float e = __expf(-u2);
    return x * __builtin_amdgcn_rcpf(1.0f + e);
}

// ---------------- fused prep: cast_x + 3 transposes (64x64) + pack_wdown -------
__global__ void __launch_bounds__(256) prep_kernel(
        const float* __restrict__ x, const float* __restrict__ w1,
        const float* __restrict__ w2, const float* __restrict__ wup,
        const float* __restrict__ wdn,
        unsigned short* __restrict__ xb, unsigned short* __restrict__ w1t,
        unsigned short* __restrict__ B2t, unsigned short* __restrict__ wdt) {
    __shared__ float tile[64][65];
    const int b = blockIdx.x, tid = threadIdx.x;
    if (b < 9408) {                      // cast x -> bf16, float4->ushort4
        int i = b * 256 + tid;
        float4 v = ((const float4*)x)[i];
        ushort4 o;
        o.x = f2bf(v.x); o.y = f2bf(v.y); o.z = f2bf(v.z); o.w = f2bf(v.w);
        ((ushort4*)xb)[i] = o;
        return;
    }
    if (b < 10584) {                     // 64x64 transpose tiles
        const float* in; unsigned short* outp; int Ccols, out_ld, out_off, bx, by;
        if (b < 9984)       { int t = b - 9408;  in = w1;  outp = w1t; Ccols = 3072; out_ld = 768;  out_off = 0;    bx = t % 48; by = t / 48; }
        else if (b < 10560) { int t = b - 9984;  in = w2;  outp = B2t; Ccols = 768;  out_ld = 3200; out_off = 0;    bx = t % 12; by = t / 12; }
        else                { int t = b - 10560; in = wup; outp = B2t; Ccols = 768;  out_ld = 3200; out_off = 3072; bx = t % 12; by = t / 12; }
        const int c0 = bx * 64, r0 = by * 64;
        #pragma unroll
        for (int p = 0; p < 4; ++p) {
            int idx = p * 256 + tid;
            int r = idx >> 4, c4 = (idx & 15) * 4;
            float4 v = *(const float4*)&in[(size_t)(r0 + r) * Ccols + c0 + c4];
            tile[r][c4 + 0] = v.x; tile[r][c4 + 1] = v.y;
            tile[r][c4 + 2] = v.z; tile[r][c4 + 3] = v.w;
        }
        __syncthreads();
        #pragma unroll
        for (int p = 0; p < 2; ++p) {
            int u = p * 256 + tid;
            int cc = u >> 3, r8 = (u & 7) * 8;
            uint4 pk;
            pk.x = (unsigned)f2bf(tile[r8 + 0][cc]) | ((unsigned)f2bf(tile[r8 + 1][cc]) << 16);
            pk.y = (unsigned)f2bf(tile[r8 + 2][cc]) | ((unsigned)f2bf(tile[r8 + 3][cc]) << 16);
            pk.z = (unsigned)f2bf(tile[r8 + 4][cc]) | ((unsigned)f2bf(tile[r8 + 5][cc]) << 16);
            pk.w = (unsigned)f2bf(tile[r8 + 6][cc]) | ((unsigned)f2bf(tile[r8 + 7][cc]) << 16);
            *(uint4*)&outp[(size_t)(c0 + cc) * out_ld + out_off + r0 + r8] = pk;
        }
        return;
    }
    {   // pack_wdown: wdt[j][c] = wdown[e][c][r], j = e*16+r
        int idx = (b - 10584) * 256 + tid;
        int j = idx / 768, c = idx - j * 768;
        int e = j >> 4, r = j & 15;
        wdt[idx] = f2bf(wdn[((size_t)e * 768 + c) * 16 + r]);
    }
}

// ---- old MFMA GEMM (R12-proven), used only for GEMMd (EPI=1, TM=128) --------
template <int EPI, int TM>
__global__ void __launch_bounds__(TM * 2)
gemm_bt_kernel(const unsigned short* __restrict__ A, int lda,
               const unsigned short* __restrict__ Bt, int ldb,
               int kIters,
               const float* __restrict__ bias,
               unsigned short* __restrict__ apOut,
               float* __restrict__ fOut,
               const int* __restrict__ tki,
               const float* __restrict__ tkp) {
    constexpr int NT    = TM * 2;          // threads
    constexpr int ABUF  = TM * 32;         // elems per A buffer
    constexpr int BBUF  = 128 * 32;        // elems per B buffer
    __shared__ __align__(16) unsigned short As[2 * ABUF];
    __shared__ __align__(16) unsigned short Bs[2 * BBUF];

    const int bx = blockIdx.x, by = blockIdx.y;
    const int tid  = threadIdx.x;
    const int wave = tid >> 6;
    const int lane = tid & 63;
    const int m0 = by * TM;
    const int n0 = bx * 128;
    const int wm = (wave >> 1) * 64;
    const int wn = (wave & 1) * 64;
    const int row16 = lane & 15;
    const int quad  = lane >> 4;
    const int kch   = quad * 8;

    f32x4 acc[4][4] = {};

    const int r_s = tid >> 2;
    const int c_s = (tid & 3) * 8;
    const size_t aRow0 = (size_t)(m0 + r_s) * lda + c_s;
    const size_t aRow1 = aRow0 + (size_t)(NT / 4) * lda;
    const size_t bRow0 = (size_t)(n0 + r_s) * ldb + c_s;
    const size_t bRow1 = bRow0 + (size_t)64 * ldb;       // used only if TM==128
    unsigned short* asB0 = &As[(wave * 64) * 8];
    unsigned short* asB1 = &As[(NT + wave * 64) * 8];
    unsigned short* bsB0 = &Bs[(wave * 64) * 8];
    unsigned short* bsB1 = &Bs[(256 + wave * 64) * 8];

    {
        GLD(A + aRow0, asB0);
        GLD(A + aRow1, asB1);
        GLD(Bt + bRow0, bsB0);
        if (TM == 128) GLD(Bt + bRow1, bsB1);
    }

    for (int kt = 0; kt < kIters; ++kt) {
        __syncthreads();

        if (kt + 1 < kIters) {
            const int k1 = (kt + 1) * 32;
            const int pa = ((kt + 1) & 1) * ABUF;
            const int pb = ((kt + 1) & 1) * BBUF;
            GLD(A + aRow0 + k1, asB0 + pa);
            GLD(A + aRow1 + k1, asB1 + pa);
            GLD(Bt + bRow0 + k1, bsB0 + pb);
            if (TM == 128) GLD(Bt + bRow1 + k1, bsB1 + pb);
        }

        const int ca = (kt & 1) * ABUF;
        const int cb = (kt & 1) * BBUF;
        bf16x8 af[4], bfr[4];
        #pragma unroll
        for (int mi = 0; mi < 4; ++mi)
            af[mi] = *(const bf16x8*)&As[ca + (wm + mi * 16 + row16) * 32 + kch];
        #pragma unroll
        for (int ni = 0; ni < 4; ++ni)
            bfr[ni] = *(const bf16x8*)&Bs[cb + (wn + ni * 16 + row16) * 32 + kch];

        #pragma unroll
        for (int mi = 0; mi < 4; ++mi)
            #pragma unroll
            for (int ni = 0; ni < 4; ++ni)
                acc[mi][ni] = __builtin_amdgcn_mfma_f32_16x16x32_bf16(
                    af[mi], bfr[ni], acc[mi][ni], 0, 0, 0);
    }

    #pragma unroll
    for (int mi = 0; mi < 4; ++mi) {
        #pragma unroll
        for (int i = 0; i < 4; ++i) {
            const int m = m0 + wm + mi * 16 + quad * 4 + i;
            int i0 = 0, i1 = 0; float p0 = 0.f, p1 = 0.f;
            if (EPI == 1) {
                i0 = tki[m * 2]; i1 = tki[m * 2 + 1];
                p0 = tkp[m * 2]; p1 = tkp[m * 2 + 1];
            }
            #pragma unroll
            for (int ni = 0; ni < 4; ++ni) {
                const int ncol = n0 + wn + ni * 16 + row16;
                float v = acc[mi][ni][i];
                if (EPI == 0) {
                    v = gelu_fast(v + bias[ncol]);
                    apOut[(size_t)m * KBIG + ncol] = f2bf(v);
                } else if (EPI == 1) {
                    const int e = ncol >> 4;
                    float wt = (i0 == e ? p0 : 0.f) + (i1 == e ? p1 : 0.f);
                    v = gelu_fast(v) * wt;
                    apOut[(size_t)m * KBIG + 3072 + ncol] = f2bf(v);
                } else {
                    fOut[(size_t)m * CDIM + ncol] = v + bias[ncol];
                }
            }
        }
    }
}

// ---- 8-phase 256 x (64*NFRAG) BK=64 GEMM (T2+T3+T4+T5), C = A * Bt^T --------
// 512 thr = 8 waves (2M x 4N); per-wave C = 128 x (16*NFRAG).
// LDS: A bufs [2]x32KB at 0, B bufs [2]x(NFRAG*8KB) after. K-tile = 64 cols;
// stored [rows][64 cols] row-major (128B rows). 3-bit swizzle byte ^=
// ((byte>>7)&7)<<4 on BOTH sides (pre-swizzled global source, swizzled
// ds_read) -> 16-row column reads hit all 8 slots: measured 0 conflicts.
// Issue slots per iteration (A issue = 2 GLD x 64 rows; B chunk = 1 GLD):
//   ph0: A1h0(t+1)  ph1: A1h1(t+1)  ph2: B0c0,c1(t+2)  ph3: B0c2..(t+2) [vm]
//   ph4: A0h0(t+2)  ph5: A0h1(t+2)  ph6: B1c0,c1(t+3)  ph7: B1c2..(t+3) [vm]
// Tail vmcnt(N): N = loads issued after the last A GLD = 2 + (NFRAG-2) =
// NFRAG -> forces the A tile read next phase + the B tile staged last iter
// landed; the NFRAG newest B loads stay outstanding. Never 0 in main loop.

template <int NFRAG, int Q, bool TAILV, class Issue>
__device__ __forceinline__ void phase8(
        const char* ldsAbuf, const char* ldsBbuf, int aFB, int bFB, int swz,
        f32x4 (&acc)[8][NFRAG], bf16x8 (&bfr)[NFRAG][2], Issue issue) {
    bf16x8 af[2][2];
    #pragma unroll
    for (int f = 0; f < 2; ++f)
        #pragma unroll
        for (int k = 0; k < 2; ++k)
            af[f][k] = *(const bf16x8*)(ldsAbuf + ((aFB + Q * 4096 + f * 2048 + k * 64) ^ swz));
    if (Q == 0) {
        #pragma unroll
        for (int nf = 0; nf < NFRAG; ++nf)
            #pragma unroll
            for (int k = 0; k < 2; ++k)
                bfr[nf][k] = *(const bf16x8*)(ldsBbuf + ((bFB + nf * 2048 + k * 64) ^ swz));
    }
    issue();
    __builtin_amdgcn_s_barrier();
    asm volatile("s_waitcnt lgkmcnt(0)" ::: "memory");
    __builtin_amdgcn_sched_barrier(0);
    __builtin_amdgcn_s_setprio(1);
    #pragma unroll
    for (int f = 0; f < 2; ++f)
        #pragma unroll
        for (int nf = 0; nf < NFRAG; ++nf)
            #pragma unroll
            for (int k = 0; k < 2; ++k)
                acc[2 * Q + f][nf] = __builtin_amdgcn_mfma_f32_16x16x32_bf16(
                    af[f][k], bfr[nf][k], acc[2 * Q + f][nf], 0, 0, 0);
    __builtin_amdgcn_s_setprio(0);
    if (TAILV) {
        if constexpr (NFRAG == 4) asm volatile("s_waitcnt vmcnt(4)" ::: "memory");
        else                      asm volatile("s_waitcnt vmcnt(3)" ::: "memory");
    }
    __builtin_amdgcn_s_barrier();
    __builtin_amdgcn_sched_barrier(0);
}

// EPI 0: gelu(acc + bias[n]) -> bf16 apOut[m*3200 + n]   (GEMM1)
// EPI 2: acc + bias[n]       -> f32  fOut[m*768 + n]     (GEMM2)
template <int EPI, int NFRAG, int NBX>
__global__ void __launch_bounds__(512, 2)
gemm8_kernel(const unsigned short* __restrict__ A, int lda,
             const unsigned short* __restrict__ Bt, int ldb,
             int kTiles, const float* __restrict__ bias,
             unsigned short* __restrict__ apOut, float* __restrict__ fOut) {
    constexpr int BBYTES = NFRAG * 8192;               // per B buffer
    __shared__ __align__(1024) char ldsraw[65536 + 2 * BBYTES];
    char* ldsA = ldsraw;
    char* ldsB = ldsraw + 65536;

    // bijective XCD swizzle (m204): nwg%8 != 0 safe. bx-fast wgid order ->
    // each XCD's contiguous chunk shares A row-panels (L2 dedup).
    const int nwg  = gridDim.x;
    const int q    = nwg >> 3, r = nwg & 7;
    const int orig = blockIdx.x;
    const int xcd  = orig & 7, within = orig >> 3;
    const int wgid = (xcd < r ? xcd * (q + 1) : r * (q + 1) + (xcd - r) * q) + within;
    const int bx = wgid % NBX, by = wgid / NBX;

    const int tid  = threadIdx.x;
    const int wave = tid >> 6;
    const int lane = tid & 63;
    const int m0 = by * 256;
    const int n0 = bx * (NFRAG * 64);
    const int row16 = lane & 15;
    const int quad  = lane >> 4;
    const int wm = (wave >> 2) << 7;            // 0 / 128
    const int wn = (wave & 3) * (NFRAG * 16);   // 4 N-waves
    // ds_read fragment bases (UNswizzled); XOR applied to fully-summed offset.
    const int swz = (row16 & 7) << 4;
    const int aFB = ((wm + row16) << 7) + (quad << 4);
    const int bFB = ((wn + row16) << 7) + (quad << 4);

    // staging: dest linear in tid (dest = wavebase + lane*16); source address
    // pre-swizzled with the same involution so LDS content is swizzle-stored.
    const int d  = tid << 4;
    const int s  = d ^ (((d >> 7) & 7) << 4);
    const int sr = s >> 7;                // source row 0..63 (per 8KB chunk)
    const int sc = (s & 127) >> 1;        // source col elem (16B chunk)
    const char* aSrc = (const char*)(A + (size_t)(m0 + sr) * lda + sc);
    const char* bSrc = (const char*)(Bt + (size_t)(n0 + sr) * ldb + sc);
    const size_t aStep = (size_t)64 * lda * 2;   // 64 rows, bytes
    const size_t bStep = (size_t)64 * ldb * 2;
    const int ldsW = wave << 10;

    auto issueA = [&](int b, int h, int tk) {    // 2 GLD = 128 rows
        const char* sp = aSrc + (size_t)(2 * h) * aStep + (size_t)tk * 128;
        char* dp = ldsA + b * 32768 + h * 16384 + ldsW;
        GLD(sp, dp);
        GLD(sp + aStep, dp + 8192);
    };
    auto issueB = [&](int b, int c, int tk) {    // 1 GLD = 64 rows
        const char* sp = bSrc + (size_t)c * bStep + (size_t)tk * 128;
        char* dp = ldsB + b * BBYTES + c * 8192 + ldsW;
        GLD(sp, dp);
    };

    f32x4 acc[8][NFRAG] = {};

    // prologue: B(0)->bufB0, A(0)->bufA0, B(1)->bufB1; leave B1 outstanding
    #pragma unroll
    for (int c = 0; c < NFRAG; ++c) issueB(0, c, 0);
    issueA(0, 0, 0); issueA(0, 1, 0);
    #pragma unroll
    for (int c = 0; c < NFRAG; ++c) issueB(1, c, 1);
    if constexpr (NFRAG == 4) asm volatile("s_waitcnt vmcnt(4)" ::: "memory");
    else                      asm volatile("s_waitcnt vmcnt(3)" ::: "memory");
    __builtin_amdgcn_s_barrier();
    __builtin_amdgcn_sched_barrier(0);

    const char* A0 = ldsA;         const char* B0 = ldsB;
    const char* A1 = ldsA + 32768; const char* B1 = ldsB + BBYTES;
    const int nIter = kTiles >> 1;
    for (int it = 0; it < nIter; ++it) {
        const int t  = it * 2;
        const int t2 = (t + 2 < kTiles) ? t + 2 : 0;   // clamped (harmless re-stage)
        const int t3 = (t + 3 < kTiles) ? t + 3 : 0;
        bf16x8 bfr[NFRAG][2];
        phase8<NFRAG, 0, false>(A0, B0, aFB, bFB, swz, acc, bfr, [&]{ issueA(1, 0, t + 1); });
        phase8<NFRAG, 1, false>(A0, B0, aFB, bFB, swz, acc, bfr, [&]{ issueA(1, 1, t + 1); });
        phase8<NFRAG, 2, false>(A0, B0, aFB, bFB, swz, acc, bfr, [&]{ issueB(0, 0, t2); issueB(0, 1, t2); });
        phase8<NFRAG, 3, true >(A0, B0, aFB, bFB, swz, acc, bfr, [&]{
            #pragma unroll
            for (int c = 2; c < NFRAG; ++c) issueB(0, c, t2); });
        phase8<NFRAG, 0, false>(A1, B1, aFB, bFB, swz, acc, bfr, [&]{ issueA(0, 0, t2); });
        phase8<NFRAG, 1, false>(A1, B1, aFB, bFB, swz, acc, bfr, [&]{ issueA(0, 1, t2); });
        phase8<NFRAG, 2, false>(A1, B1, aFB, bFB, swz, acc, bfr, [&]{ issueB(1, 0, t3); issueB(1, 1, t3); });
        phase8<NFRAG, 3, true >(A1, B1, aFB, bFB, swz, acc, bfr, [&]{
            #pragma unroll
            for (int c = 2; c < NFRAG; ++c) issueB(1, c, t3); });
    }
    asm volatile("s_waitcnt vmcnt(0)" ::: "memory");

    // epilogue: C/D layout col = row16 + nf*16, row = quad*4 + i (+ mi*16)
    float bv[NFRAG];
    #pragma unroll
    for (int nf = 0; nf < NFRAG; ++nf) bv[nf] = bias[n0 + wn + nf * 16 + row16];
    #pragma unroll
    for (int mi = 0; mi < 8; ++mi) {
        #pragma unroll
        for (int i = 0; i < 4; ++i) {
            const int m = m0 + wm + mi * 16 + quad * 4 + i;
            #pragma unroll
            for (int nf = 0; nf < NFRAG; ++nf) {
                const int col = n0 + wn + nf * 16 + row16;
                float v = acc[mi][nf][i] + bv[nf];
                if (EPI == 0) apOut[(size_t)m * KBIG + col] = f2bf(gelu_fast(v));
                else          fOut[(size_t)m * CDIM + col] = v;
            }
        }
    }
}

// ---------------- launch ----------------

extern "C" void kernel_launch(void* const* d_in, const int* in_sizes, int n_in,
                              void* d_out, int out_size, void* d_ws, size_t ws_size,
                              hipStream_t stream) {
    const float* x   = (const float*)d_in[0];
    const float* tkp = (const float*)d_in[1];
    const int*   tki = (const int*)d_in[2];
    const float* w1  = (const float*)d_in[3];
    const float* b1  = (const float*)d_in[4];
    const float* w2  = (const float*)d_in[5];
    const float* b2  = (const float*)d_in[6];
    const float* wdn = (const float*)d_in[7];
    const float* wup = (const float*)d_in[8];
    float* out = (float*)d_out;

    unsigned short* xb  = (unsigned short*)d_ws;
    unsigned short* w1t = xb  + (size_t)NTOK * CDIM;      // 3072 x 768
    unsigned short* B2t = w1t + (size_t)HIDDIM * CDIM;    // 768 x 3200
    unsigned short* wdt = B2t + (size_t)CDIM * KBIG;      // 128 x 768
    unsigned short* Ap  = wdt + (size_t)128 * CDIM;       // 12544 x 3200

    prep_kernel<<<dim3(10968), 256, 0, stream>>>(x, w1, w2, wup, wdn,
                                                 xb, w1t, B2t, wdt);

    // GEMMd: sd -> Ap[:, 3072:3200] ; 98 blocks, proven R12 kernel
    gemm_bt_kernel<1, 128><<<dim3(1, NTOK / 128), 256, 0, stream>>>(
        xb, CDIM, wdt, CDIM, CDIM / 32, nullptr, Ap, nullptr, tki, tkp);
    // GEMM1: h -> Ap[:, 0:3072] ; 8-phase 256x256, 588 blocks XCD-swizzled
    gemm8_kernel<0, 4, HIDDIM / 256><<<dim3((HIDDIM / 256) * (NTOK / 256)), 512, 0, stream>>>(
        xb, CDIM, w1t, CDIM, CDIM / 64, b1, Ap, nullptr);
    // GEMM2: out = Ap @ B2t^T + b2 ; 8-phase 256x192, 196 blocks XCD-swizzled
    gemm8_kernel<2, 3, CDIM / 192><<<dim3((CDIM / 192) * (NTOK / 256)), 512, 0, stream>>>(
        Ap, KBIG, B2t, KBIG, KBIG / 64, b2, nullptr, out);
}

// Round 5
// 264.216 us; speedup vs baseline: 1.2393x; 1.0285x over previous
//
#include <hip/hip_runtime.h>
#include <hip/hip_bf16.h>
#include <math.h>

// ConvNeXt MLP + parallel MoE-LoRA, fp32 in/out, bf16-tolerance harness.
// B,H,W,C = 64,14,14,768 ; N_tok = 12544 = 98*128 ; HID = 3072 ; E=8,K=2,R=16.
//
//   h  = gelu(x @ w1 + b1)                GEMM1  [12544,768]x[768,3072]
//   sd = wt * gelu(x @ wdown)             GEMMd  [12544,768]x[768,128]
//   out = [h | sd] @ [w2 ; wup] + b2      GEMM2  [12544,3200]x[3200,768]
//
// R17: R16 post-mortem: GEMM1 stuck at 89.5us. 128KB LDS = 1 block/CU ->
// 588 blocks in 3 lockstep rounds (23% quantization tax) and nothing fills
// the serialized {ds_read -> barrier -> lgkmcnt(0) -> MFMA} phase stalls
// (MfmaUtil 27%). Fix: retile both big GEMMs to 128x192 BK=64 = 80KB LDS
// -> 2 resident blocks/CU (16 waves/CU, launch_bounds(512,4)); cross-block
// overlap fills barrier/vmcnt/LDS stalls. 4-phase iteration (2 k-tiles),
// counted vmcnt(3) tails (outstanding peaks 8, never drains to 0), 3-bit
// both-sides LDS swizzle kept (0 conflicts), XCD-bijective grid swizzle
// kept (1568 & 392 blocks). ds_read addrs precomputed as XOR-folded ints
// (k*64 folded before XOR; 2048-multiples commute) - no VALU on the
// lgkmcnt-gated path. Register budget: acc 48 + bfr 24 + af 16 <= 128.

#define NTOK   12544
#define CDIM   768
#define HIDDIM 3072
#define KBIG   3200

typedef __attribute__((ext_vector_type(8))) short bf16x8;
typedef __attribute__((ext_vector_type(4))) float f32x4;

#define GLOBAL_AS(p) ((const __attribute__((address_space(1))) void*)(p))
#define LDS_AS(p)    ((__attribute__((address_space(3))) void*)(p))
#define GLD(src, dst) __builtin_amdgcn_global_load_lds(GLOBAL_AS(src), LDS_AS(dst), 16, 0, 0)

__device__ inline unsigned short f2bf(float f) {
    unsigned int x = __float_as_uint(f);
    x += 0x7fffu + ((x >> 16) & 1u);   // RNE
    return (unsigned short)(x >> 16);
}

// tanh-form GELU, branch-free; max |err| ~4.3e-4 vs exact erf form.
__device__ inline float gelu_fast(float x) {
    float x3 = x * x * x;
    float u2 = 1.5957691216057308f * x + 0.07135481627260025f * x3;
    float e = __expf(-u2);
    return x * __builtin_amdgcn_rcpf(1.0f + e);
}

// ---------------- fused prep: cast_x + 3 transposes (64x64) + pack_wdown -------
__global__ void __launch_bounds__(256) prep_kernel(
        const float* __restrict__ x, const float* __restrict__ w1,
        const float* __restrict__ w2, const float* __restrict__ wup,
        const float* __restrict__ wdn,
        unsigned short* __restrict__ xb, unsigned short* __restrict__ w1t,
        unsigned short* __restrict__ B2t, unsigned short* __restrict__ wdt) {
    __shared__ float tile[64][65];
    const int b = blockIdx.x, tid = threadIdx.x;
    if (b < 9408) {                      // cast x -> bf16, float4->ushort4
        int i = b * 256 + tid;
        float4 v = ((const float4*)x)[i];
        ushort4 o;
        o.x = f2bf(v.x); o.y = f2bf(v.y); o.z = f2bf(v.z); o.w = f2bf(v.w);
        ((ushort4*)xb)[i] = o;
        return;
    }
    if (b < 10584) {                     // 64x64 transpose tiles
        const float* in; unsigned short* outp; int Ccols, out_ld, out_off, bx, by;
        if (b < 9984)       { int t = b - 9408;  in = w1;  outp = w1t; Ccols = 3072; out_ld = 768;  out_off = 0;    bx = t % 48; by = t / 48; }
        else if (b < 10560) { int t = b - 9984;  in = w2;  outp = B2t; Ccols = 768;  out_ld = 3200; out_off = 0;    bx = t % 12; by = t / 12; }
        else                { int t = b - 10560; in = wup; outp = B2t; Ccols = 768;  out_ld = 3200; out_off = 3072; bx = t % 12; by = t / 12; }
        const int c0 = bx * 64, r0 = by * 64;
        #pragma unroll
        for (int p = 0; p < 4; ++p) {
            int idx = p * 256 + tid;
            int r = idx >> 4, c4 = (idx & 15) * 4;
            float4 v = *(const float4*)&in[(size_t)(r0 + r) * Ccols + c0 + c4];
            tile[r][c4 + 0] = v.x; tile[r][c4 + 1] = v.y;
            tile[r][c4 + 2] = v.z; tile[r][c4 + 3] = v.w;
        }
        __syncthreads();
        #pragma unroll
        for (int p = 0; p < 2; ++p) {
            int u = p * 256 + tid;
            int cc = u >> 3, r8 = (u & 7) * 8;
            uint4 pk;
            pk.x = (unsigned)f2bf(tile[r8 + 0][cc]) | ((unsigned)f2bf(tile[r8 + 1][cc]) << 16);
            pk.y = (unsigned)f2bf(tile[r8 + 2][cc]) | ((unsigned)f2bf(tile[r8 + 3][cc]) << 16);
            pk.z = (unsigned)f2bf(tile[r8 + 4][cc]) | ((unsigned)f2bf(tile[r8 + 5][cc]) << 16);
            pk.w = (unsigned)f2bf(tile[r8 + 6][cc]) | ((unsigned)f2bf(tile[r8 + 7][cc]) << 16);
            *(uint4*)&outp[(size_t)(c0 + cc) * out_ld + out_off + r0 + r8] = pk;
        }
        return;
    }
    {   // pack_wdown: wdt[j][c] = wdown[e][c][r], j = e*16+r
        int idx = (b - 10584) * 256 + tid;
        int j = idx / 768, c = idx - j * 768;
        int e = j >> 4, r = j & 15;
        wdt[idx] = f2bf(wdn[((size_t)e * 768 + c) * 16 + r]);
    }
}

// ---- old MFMA GEMM (R12-proven), used only for GEMMd (EPI=1, TM=128) --------
template <int EPI, int TM>
__global__ void __launch_bounds__(TM * 2)
gemm_bt_kernel(const unsigned short* __restrict__ A, int lda,
               const unsigned short* __restrict__ Bt, int ldb,
               int kIters,
               const float* __restrict__ bias,
               unsigned short* __restrict__ apOut,
               float* __restrict__ fOut,
               const int* __restrict__ tki,
               const float* __restrict__ tkp) {
    constexpr int NT    = TM * 2;          // threads
    constexpr int ABUF  = TM * 32;         // elems per A buffer
    constexpr int BBUF  = 128 * 32;        // elems per B buffer
    __shared__ __align__(16) unsigned short As[2 * ABUF];
    __shared__ __align__(16) unsigned short Bs[2 * BBUF];

    const int bx = blockIdx.x, by = blockIdx.y;
    const int tid  = threadIdx.x;
    const int wave = tid >> 6;
    const int lane = tid & 63;
    const int m0 = by * TM;
    const int n0 = bx * 128;
    const int wm = (wave >> 1) * 64;
    const int wn = (wave & 1) * 64;
    const int row16 = lane & 15;
    const int quad  = lane >> 4;
    const int kch   = quad * 8;

    f32x4 acc[4][4] = {};

    const int r_s = tid >> 2;
    const int c_s = (tid & 3) * 8;
    const size_t aRow0 = (size_t)(m0 + r_s) * lda + c_s;
    const size_t aRow1 = aRow0 + (size_t)(NT / 4) * lda;
    const size_t bRow0 = (size_t)(n0 + r_s) * ldb + c_s;
    const size_t bRow1 = bRow0 + (size_t)64 * ldb;       // used only if TM==128
    unsigned short* asB0 = &As[(wave * 64) * 8];
    unsigned short* asB1 = &As[(NT + wave * 64) * 8];
    unsigned short* bsB0 = &Bs[(wave * 64) * 8];
    unsigned short* bsB1 = &Bs[(256 + wave * 64) * 8];

    {
        GLD(A + aRow0, asB0);
        GLD(A + aRow1, asB1);
        GLD(Bt + bRow0, bsB0);
        if (TM == 128) GLD(Bt + bRow1, bsB1);
    }

    for (int kt = 0; kt < kIters; ++kt) {
        __syncthreads();

        if (kt + 1 < kIters) {
            const int k1 = (kt + 1) * 32;
            const int pa = ((kt + 1) & 1) * ABUF;
            const int pb = ((kt + 1) & 1) * BBUF;
            GLD(A + aRow0 + k1, asB0 + pa);
            GLD(A + aRow1 + k1, asB1 + pa);
            GLD(Bt + bRow0 + k1, bsB0 + pb);
            if (TM == 128) GLD(Bt + bRow1 + k1, bsB1 + pb);
        }

        const int ca = (kt & 1) * ABUF;
        const int cb = (kt & 1) * BBUF;
        bf16x8 af[4], bfr[4];
        #pragma unroll
        for (int mi = 0; mi < 4; ++mi)
            af[mi] = *(const bf16x8*)&As[ca + (wm + mi * 16 + row16) * 32 + kch];
        #pragma unroll
        for (int ni = 0; ni < 4; ++ni)
            bfr[ni] = *(const bf16x8*)&Bs[cb + (wn + ni * 16 + row16) * 32 + kch];

        #pragma unroll
        for (int mi = 0; mi < 4; ++mi)
            #pragma unroll
            for (int ni = 0; ni < 4; ++ni)
                acc[mi][ni] = __builtin_amdgcn_mfma_f32_16x16x32_bf16(
                    af[mi], bfr[ni], acc[mi][ni], 0, 0, 0);
    }

    #pragma unroll
    for (int mi = 0; mi < 4; ++mi) {
        #pragma unroll
        for (int i = 0; i < 4; ++i) {
            const int m = m0 + wm + mi * 16 + quad * 4 + i;
            int i0 = 0, i1 = 0; float p0 = 0.f, p1 = 0.f;
            if (EPI == 1) {
                i0 = tki[m * 2]; i1 = tki[m * 2 + 1];
                p0 = tkp[m * 2]; p1 = tkp[m * 2 + 1];
            }
            #pragma unroll
            for (int ni = 0; ni < 4; ++ni) {
                const int ncol = n0 + wn + ni * 16 + row16;
                float v = acc[mi][ni][i];
                if (EPI == 0) {
                    v = gelu_fast(v + bias[ncol]);
                    apOut[(size_t)m * KBIG + ncol] = f2bf(v);
                } else if (EPI == 1) {
                    const int e = ncol >> 4;
                    float wt = (i0 == e ? p0 : 0.f) + (i1 == e ? p1 : 0.f);
                    v = gelu_fast(v) * wt;
                    apOut[(size_t)m * KBIG + 3072 + ncol] = f2bf(v);
                } else {
                    fOut[(size_t)m * CDIM + ncol] = v + bias[ncol];
                }
            }
        }
    }
}

// ---- 4-phase 128x192 BK=64 GEMM, 80KB LDS, 2 blocks/CU, C = A * Bt^T --------
// 512 thr = 8 waves (2M x 4N); per-wave C = 64x48 (acc[4][3] f32x4).
// LDS 80KB: A bufs [2]x16KB at 0, B bufs [2]x24KB at +32KB. K-tile = 64 cols,
// stored [rows][64] row-major (128B rows). 3-bit swizzle byte ^=
// ((byte>>7)&7)<<4 on BOTH sides (pre-swizzled global source, swizzled
// ds_read offsets) -> column-slice reads conflict-free (R15: 5.6M -> 0).
// Iteration = 2 k-tiles, 4 phases; per phase 12 MFMA. Issue schedule:
//   ph0 (t@buf0,P0): issue A(t+1)->a1   [2 GLD]
//   ph1 (t@buf0,P1): issue B(t+2)->b0   [3 GLD]  TAIL vmcnt(3)
//   ph2 (t+1@buf1,P0): issue A(t+2)->a0 [2 GLD]
//   ph3 (t+1@buf1,P1): issue B(t+3)->b1 [3 GLD]  TAIL vmcnt(3)
// Outstanding peaks at 8; vmcnt(3) forces exactly the next tile's A+B landed
// (B prefetched 2 ahead is safe: B is reg-consumed in P0 before overwrite).
// Never drains to 0 in the main loop.

template <int P, bool TAILV, class Issue>
__device__ __forceinline__ void phase4(
        const char* lds, int aO0, int aO1, int bO0, int bO1,
        f32x4 (&acc)[4][3], bf16x8 (&bfr)[3][2], Issue issue) {
    bf16x8 af[2][2];
    #pragma unroll
    for (int f = 0; f < 2; ++f) {
        af[f][0] = *(const bf16x8*)(lds + aO0 + (2 * P + f) * 2048);
        af[f][1] = *(const bf16x8*)(lds + aO1 + (2 * P + f) * 2048);
    }
    if (P == 0) {
        #pragma unroll
        for (int nf = 0; nf < 3; ++nf) {
            bfr[nf][0] = *(const bf16x8*)(lds + bO0 + nf * 2048);
            bfr[nf][1] = *(const bf16x8*)(lds + bO1 + nf * 2048);
        }
    }
    issue();
    __builtin_amdgcn_s_barrier();
    asm volatile("s_waitcnt lgkmcnt(0)" ::: "memory");
    __builtin_amdgcn_sched_barrier(0);
    __builtin_amdgcn_s_setprio(1);
    #pragma unroll
    for (int f = 0; f < 2; ++f)
        #pragma unroll
        for (int nf = 0; nf < 3; ++nf)
            #pragma unroll
            for (int k = 0; k < 2; ++k)
                acc[2 * P + f][nf] = __builtin_amdgcn_mfma_f32_16x16x32_bf16(
                    af[f][k], bfr[nf][k], acc[2 * P + f][nf], 0, 0, 0);
    __builtin_amdgcn_s_setprio(0);
    if (TAILV) asm volatile("s_waitcnt vmcnt(3)" ::: "memory");
    __builtin_amdgcn_s_barrier();
    __builtin_amdgcn_sched_barrier(0);
}

// EPI 0: gelu(acc + bias[n]) -> bf16 apOut[m*3200 + n]   (GEMM1)
// EPI 2: acc + bias[n]       -> f32  fOut[m*768 + n]     (GEMM2)
template <int EPI, int NBX>
__global__ void __launch_bounds__(512, 4)
gemm4_kernel(const unsigned short* __restrict__ A, int lda,
             const unsigned short* __restrict__ Bt, int ldb,
             int kTiles, const float* __restrict__ bias,
             unsigned short* __restrict__ apOut, float* __restrict__ fOut) {
    __shared__ __align__(1024) char ldsraw[81920];     // 80 KiB -> 2 blocks/CU
    char* ldsA = ldsraw;                                // [2] x 16 KB
    char* ldsB = ldsraw + 32768;                        // [2] x 24 KB

    // bijective XCD swizzle (m204; exact for nwg%8==0 too), bx-fast order:
    // each XCD's contiguous wgid chunk shares A row-panels (L2 dedup).
    const int nwg  = gridDim.x;
    const int q    = nwg >> 3, r = nwg & 7;
    const int orig = blockIdx.x;
    const int xcd  = orig & 7, within = orig >> 3;
    const int wgid = (xcd < r ? xcd * (q + 1) : r * (q + 1) + (xcd - r) * q) + within;
    const int bx = wgid % NBX, by = wgid / NBX;

    const int tid  = threadIdx.x;
    const int wave = tid >> 6;
    const int lane = tid & 63;
    const int m0 = by * 128;
    const int n0 = bx * 192;
    const int row16 = lane & 15;
    const int quad  = lane >> 4;
    const int wm = (wave >> 2) << 6;      // 0 / 64
    const int wn = (wave & 3) * 48;       // 0 / 48 / 96 / 144
    // ds_read offsets: XOR applied to (base + k*64); the (2P+f)*2048 /
    // nf*2048 terms are >= bit 11, disjoint from XOR bits 4-6 -> fold after.
    const int swz = (row16 & 7) << 4;
    const int aFB = ((wm + row16) << 7) + (quad << 4);
    const int bFB = ((wn + row16) << 7) + (quad << 4);
    const int aX0 = (aFB ^ swz),        aX1 = ((aFB + 64) ^ swz);
    const int bX0 = (bFB ^ swz) + 32768, bX1 = ((bFB + 64) ^ swz) + 32768;

    // staging: dest linear in tid; source pre-swizzled with same involution.
    const int d  = tid << 4;
    const int s  = d ^ (((d >> 7) & 7) << 4);
    const int sr = s >> 7;                // source row 0..63 (per 8KB unit)
    const int sc = (s & 127) >> 1;        // source col elem (16B chunk)
    const char* aSrc = (const char*)(A + (size_t)(m0 + sr) * lda + sc);
    const char* bSrc = (const char*)(Bt + (size_t)(n0 + sr) * ldb + sc);
    const size_t aStep = (size_t)64 * lda * 2;   // 64 rows, bytes
    const size_t bStep = (size_t)64 * ldb * 2;
    const int ldsW = wave << 10;

    auto issueA = [&](int b, int tk) {           // 128 rows = 2 GLD
        const char* sp = aSrc + (size_t)tk * 128;
        char* dp = ldsA + b * 16384 + ldsW;
        GLD(sp, dp);
        GLD(sp + aStep, dp + 8192);
    };
    auto issueB = [&](int b, int tk) {           // 192 rows = 3 GLD
        const char* sp = bSrc + (size_t)tk * 128;
        char* dp = ldsB + b * 24576 + ldsW;
        GLD(sp, dp);
        GLD(sp + bStep, dp + 8192);
        GLD(sp + 2 * bStep, dp + 16384);
    };

    f32x4 acc[4][3] = {};

    // prologue: B(0)->b0, A(0)->a0, B(1)->b1; leave B(1)'s 3 outstanding
    issueB(0, 0);
    issueA(0, 0);
    issueB(1, 1);
    asm volatile("s_waitcnt vmcnt(3)" ::: "memory");
    __builtin_amdgcn_s_barrier();
    __builtin_amdgcn_sched_barrier(0);

    const int nIter = kTiles >> 1;
    for (int it = 0; it < nIter; ++it) {
        const int t  = it * 2;
        const int t2 = (t + 2 < kTiles) ? t + 2 : 0;   // clamped (harmless re-stage)
        const int t3 = (t + 3 < kTiles) ? t + 3 : 0;
        bf16x8 bfr[3][2];
        phase4<0, false>(ldsraw, aX0, aX1, bX0, bX1, acc, bfr,
                         [&]{ issueA(1, t + 1); });
        phase4<1, true >(ldsraw, aX0, aX1, bX0, bX1, acc, bfr,
                         [&]{ issueB(0, t2); });
        phase4<0, false>(ldsraw, aX0 + 16384, aX1 + 16384, bX0 + 24576, bX1 + 24576, acc, bfr,
                         [&]{ issueA(0, t2); });
        phase4<1, true >(ldsraw, aX0 + 16384, aX1 + 16384, bX0 + 24576, bX1 + 24576, acc, bfr,
                         [&]{ issueB(1, t3); });
    }
    asm volatile("s_waitcnt vmcnt(0)" ::: "memory");

    // epilogue: C/D layout col = row16 + nf*16, row = quad*4 + i (+ mi*16)
    float bv[3];
    #pragma unroll
    for (int nf = 0; nf < 3; ++nf) bv[nf] = bias[n0 + wn + nf * 16 + row16];
    #pragma unroll
    for (int mi = 0; mi < 4; ++mi) {
        #pragma unroll
        for (int i = 0; i < 4; ++i) {
            const int m = m0 + wm + mi * 16 + quad * 4 + i;
            #pragma unroll
            for (int nf = 0; nf < 3; ++nf) {
                const int col = n0 + wn + nf * 16 + row16;
                float v = acc[mi][nf][i] + bv[nf];
                if (EPI == 0) apOut[(size_t)m * KBIG + col] = f2bf(gelu_fast(v));
                else          fOut[(size_t)m * CDIM + col] = v;
            }
        }
    }
}

// ---------------- launch ----------------

extern "C" void kernel_launch(void* const* d_in, const int* in_sizes, int n_in,
                              void* d_out, int out_size, void* d_ws, size_t ws_size,
                              hipStream_t stream) {
    const float* x   = (const float*)d_in[0];
    const float* tkp = (const float*)d_in[1];
    const int*   tki = (const int*)d_in[2];
    const float* w1  = (const float*)d_in[3];
    const float* b1  = (const float*)d_in[4];
    const float* w2  = (const float*)d_in[5];
    const float* b2  = (const float*)d_in[6];
    const float* wdn = (const float*)d_in[7];
    const float* wup = (const float*)d_in[8];
    float* out = (float*)d_out;

    unsigned short* xb  = (unsigned short*)d_ws;
    unsigned short* w1t = xb  + (size_t)NTOK * CDIM;      // 3072 x 768
    unsigned short* B2t = w1t + (size_t)HIDDIM * CDIM;    // 768 x 3200
    unsigned short* wdt = B2t + (size_t)CDIM * KBIG;      // 128 x 768
    unsigned short* Ap  = wdt + (size_t)128 * CDIM;       // 12544 x 3200

    prep_kernel<<<dim3(10968), 256, 0, stream>>>(x, w1, w2, wup, wdn,
                                                 xb, w1t, B2t, wdt);

    // GEMMd: sd -> Ap[:, 3072:3200] ; 98 blocks, proven R12 kernel
    gemm_bt_kernel<1, 128><<<dim3(1, NTOK / 128), 256, 0, stream>>>(
        xb, CDIM, wdt, CDIM, CDIM / 32, nullptr, Ap, nullptr, tki, tkp);
    // GEMM1: h -> Ap[:, 0:3072] ; 128x192, 2 blocks/CU, 1568 blocks swizzled
    gemm4_kernel<0, HIDDIM / 192><<<dim3((HIDDIM / 192) * (NTOK / 128)), 512, 0, stream>>>(
        xb, CDIM, w1t, CDIM, CDIM / 64, b1, Ap, nullptr);
    // GEMM2: out = Ap @ B2t^T + b2 ; 128x192, 2 blocks/CU, 392 blocks swizzled
    gemm4_kernel<2, CDIM / 192><<<dim3((CDIM / 192) * (NTOK / 128)), 512, 0, stream>>>(
        Ap, KBIG, B2t, KBIG, KBIG / 64, b2, nullptr, out);
}